// Round 1
// baseline (2646.276 us; speedup 1.0000x reference)
//
#include <hip/hip_runtime.h>
#include <math.h>

// ValueNetwork forward, fp32.
// ws layout (floats):
//  f    [64][32][128]        @ 0        (262144)   f[b][c][n] = in_out[b][n][c]
//  R    [64][3][64][128]     @ 262144   (1572864)  row-term of conv1, per j-border-class
//  C    [64][3][64][128]     @ 1835008  (1572864)  col-term of conv1, per i-border-class
//  D    [64][64][128][5]     @ 3407872  (2621440)  diagonal band of conv1, t=j-i+2
//  afa  [64][32][128]        @ 6029312  (262144)
//  smi  [64][128][64]        @ 6291456  (524288)   sort_mlp_input
//  wts  [64][128]            @ 6815744  (8192)
//  rh   [64][64][128]        @ 6823936  (524288)   r * h0
//  hnm  [64][64]             @ 7348224  (4096)
// total 7352320 floats = 29.4 MB

__global__ __launch_bounds__(128) void k1_front(
    const float* __restrict__ state, const float* __restrict__ w_in1,
    const float* __restrict__ b_in1, const float* __restrict__ w_in2,
    const float* __restrict__ b_in2, float* __restrict__ f) {
  int b = blockIdx.x, n = threadIdx.x;
  const float* st = state + (b * 128 + n) * 13 + 6;
  float a[7];
#pragma unroll
  for (int k = 0; k < 7; k++) a[k] = st[k];
  float h[64];
  for (int o = 0; o < 64; o++) {
    float acc = b_in1[o];
#pragma unroll
    for (int k = 0; k < 7; k++) acc += w_in1[o * 7 + k] * a[k];
    h[o] = fmaxf(acc, 0.f);
  }
  for (int c = 0; c < 32; c++) {
    float acc = b_in2[c];
#pragma unroll 8
    for (int k = 0; k < 64; k++) acc += w_in2[c * 64 + k] * h[k];
    f[(b * 32 + c) * 128 + n] = fmaxf(acc, 0.f);
  }
}

// conv1 low-rank precompute. grid (o=64, b=64), 128 threads = i.
__global__ __launch_bounds__(128) void k2_pre(
    const float* __restrict__ f, const float* __restrict__ w_c1,
    float* __restrict__ R, float* __restrict__ C, float* __restrict__ D) {
  int o = blockIdx.x, b = blockIdx.y, t = threadIdx.x;
  __shared__ float fL[32 * 128];
  __shared__ float w1s[32 * 9];
  __shared__ float wrow[32 * 9];  // [c][di][jc]
  __shared__ float wcol[32 * 9];  // [c][dj][ic]
  for (int idx = t; idx < 4096; idx += 128) fL[idx] = f[b * 4096 + idx];
  for (int idx = t; idx < 288; idx += 128) w1s[idx] = w_c1[o * 288 + idx];
  __syncthreads();
  if (t < 32) {
    int c = t;
#pragma unroll
    for (int di = 0; di < 3; di++) {
      float w0 = w1s[c * 9 + di * 3 + 0], w1 = w1s[c * 9 + di * 3 + 1],
            w2 = w1s[c * 9 + di * 3 + 2];
      wrow[(c * 3 + di) * 3 + 0] = w1 + w2;       // j==0: dj in {1,2}
      wrow[(c * 3 + di) * 3 + 1] = w0 + w1 + w2;  // interior
      wrow[(c * 3 + di) * 3 + 2] = w0 + w1;       // j==127
    }
#pragma unroll
    for (int dj = 0; dj < 3; dj++) {
      float w0 = w1s[c * 9 + 0 * 3 + dj], w1 = w1s[c * 9 + 1 * 3 + dj],
            w2 = w1s[c * 9 + 2 * 3 + dj];
      wcol[(c * 3 + dj) * 3 + 0] = w1 + w2;
      wcol[(c * 3 + dj) * 3 + 1] = w0 + w1 + w2;
      wcol[(c * 3 + dj) * 3 + 2] = w0 + w1;
    }
  }
  __syncthreads();
  int i = t;
  float r0 = 0, r1 = 0, r2 = 0, c0 = 0, c1 = 0, c2 = 0;
  float d0 = 0, d1 = 0, d2 = 0, d3 = 0, d4 = 0;
  for (int c = 0; c < 32; c++) {
    float fm = (i >= 1) ? fL[c * 128 + i - 1] : 0.f;   // di=0 (y=i-1)
    float f0 = fL[c * 128 + i];                        // di=1
    float fp = (i < 127) ? fL[c * 128 + i + 1] : 0.f;  // di=2
    const float* wr = &wrow[c * 9];
    r0 += fm * wr[0] + f0 * wr[3] + fp * wr[6];
    r1 += fm * wr[1] + f0 * wr[4] + fp * wr[7];
    r2 += fm * wr[2] + f0 * wr[5] + fp * wr[8];
    const float* wc = &wcol[c * 9];
    c0 += fm * wc[0] + f0 * wc[3] + fp * wc[6];
    c1 += fm * wc[1] + f0 * wc[4] + fp * wc[7];
    c2 += fm * wc[2] + f0 * wc[5] + fp * wc[8];
    const float* wp = &w1s[c * 9];  // [di*3+dj]
    d0 += fm * wp[2];                                 // t=-2: (0,2)
    d1 += fm * wp[1] + f0 * wp[5];                    // t=-1: (0,1),(1,2)
    d2 += fm * wp[0] + f0 * wp[4] + fp * wp[8];       // t= 0: (0,0),(1,1),(2,2)
    d3 += f0 * wp[3] + fp * wp[7];                    // t=+1: (1,0),(2,1)
    d4 += fp * wp[6];                                 // t=+2: (2,0)
  }
  R[((b * 3 + 0) * 64 + o) * 128 + i] = r0;
  R[((b * 3 + 1) * 64 + o) * 128 + i] = r1;
  R[((b * 3 + 2) * 64 + o) * 128 + i] = r2;
  C[((b * 3 + 0) * 64 + o) * 128 + i] = c0;
  C[((b * 3 + 1) * 64 + o) * 128 + i] = c1;
  C[((b * 3 + 2) * 64 + o) * 128 + i] = c2;
  float* dp = &D[((b * 64 + o) * 128 + i) * 5];
  dp[0] = d0; dp[1] = d1; dp[2] = d2; dp[3] = d3; dp[4] = d4;
}

// Fused conv2 + bias + softmax(j) + afa. grid (i=128, b=64), 128 threads.
// thread: jj = t&15 (j-tile of 8), oo = t>>4 (o2-tile of 4). acc[4][8].
__global__ __launch_bounds__(128) void k3_conv2(
    const float* __restrict__ f, const float* __restrict__ R,
    const float* __restrict__ C, const float* __restrict__ D,
    const float* __restrict__ b_c1, const float* __restrict__ w_c2,
    const float* __restrict__ b_c2, float* __restrict__ afa) {
  int i = blockIdx.x, b = blockIdx.y, t = threadIdx.x;
  int jj = t & 15, oo = t >> 4;
  __shared__ float buf[12288];  // 48 KB: [0..6143]=w2s, [6144..12287]=gs; fL at end
  float* w2s = buf;             // [cc][o2][r*4+x], x<3 valid
  float* gs = buf + 6144;       // [r][cc][j]
  float acc[4][8];
#pragma unroll
  for (int o = 0; o < 4; o++)
#pragma unroll
    for (int m = 0; m < 8; m++) acc[o][m] = 0.f;

  for (int ck = 0; ck < 4; ++ck) {
    for (int idx = t; idx < 6144; idx += 128) {
      int x = idx & 3, r = (idx >> 2) % 3, o2 = (idx / 12) & 31, cc = idx / 384;
      w2s[idx] = (x < 3) ? w_c2[o2 * 576 + (ck * 16 + cc) * 9 + r * 3 + x] : 0.f;
    }
    for (int idx = t; idx < 6144; idx += 128) {
      int j = idx & 127, cc = (idx >> 7) & 15, r = idx >> 11;
      int ip = i + r - 1;
      float val = 0.f;
      if (ip >= 0 && ip < 128) {
        int o = ck * 16 + cc;
        int jc = (j == 0) ? 0 : ((j == 127) ? 2 : 1);
        int ic = (ip == 0) ? 0 : ((ip == 127) ? 2 : 1);
        float v = R[((b * 3 + jc) * 64 + o) * 128 + ip] -
                  C[((b * 3 + ic) * 64 + o) * 128 + j] + b_c1[o];
        int tt = j - ip + 2;
        if (tt >= 0 && tt <= 4) v += D[((b * 64 + o) * 128 + ip) * 5 + tt];
        val = fmaxf(v, 0.f);
      }
      gs[idx] = val;
    }
    __syncthreads();
    int j0 = jj * 8;
    for (int cc = 0; cc < 16; ++cc) {
#pragma unroll
      for (int r = 0; r < 3; r++) {
        const float* gb = &gs[(r * 16 + cc) * 128];
        float win[10];
        win[0] = (j0 > 0) ? gb[j0 - 1] : 0.f;
        float4 ga = *(const float4*)&gb[j0];
        float4 gc = *(const float4*)&gb[j0 + 4];
        win[1] = ga.x; win[2] = ga.y; win[3] = ga.z; win[4] = ga.w;
        win[5] = gc.x; win[6] = gc.y; win[7] = gc.z; win[8] = gc.w;
        win[9] = (j0 + 8 < 128) ? gb[j0 + 8] : 0.f;
#pragma unroll
        for (int o = 0; o < 4; o++) {
          float4 wv = *(const float4*)&w2s[(cc * 32 + (oo * 4 + o)) * 12 + r * 4];
#pragma unroll
          for (int m = 0; m < 8; m++)
            acc[o][m] += wv.x * win[m] + wv.y * win[m + 1] + wv.z * win[m + 2];
        }
      }
    }
    __syncthreads();
  }
  // reload f[b] into LDS (gs/w2s dead now)
  for (int idx = t; idx < 4096; idx += 128) buf[idx] = f[b * 4096 + idx];
  __syncthreads();
  const float* fL = buf;
#pragma unroll
  for (int o = 0; o < 4; o++) {
    int o2 = oo * 4 + o;
    float bias = b_c2[o2];
    float mx = -3.0e38f;
#pragma unroll
    for (int m = 0; m < 8; m++) {
      acc[o][m] += bias;
      mx = fmaxf(mx, acc[o][m]);
    }
    for (int d = 8; d >= 1; d >>= 1) mx = fmaxf(mx, __shfl_xor(mx, d, 16));
    float s = 0.f;
#pragma unroll
    for (int m = 0; m < 8; m++) {
      float e = expf(acc[o][m] - mx);
      acc[o][m] = e;
      s += e;
    }
    for (int d = 8; d >= 1; d >>= 1) s += __shfl_xor(s, d, 16);
    float inv = 1.f / s;
    float fi = fL[o2 * 128 + i];
    float part = 0.f;
#pragma unroll
    for (int m = 0; m < 8; m++) {
      int j = jj * 8 + m;
      float w = acc[o][m] * inv;
      part += w * (fi - fL[o2 * 128 + j]);
      if (j == i) part += w * fi;  // diagonal of pair
    }
    for (int d = 8; d >= 1; d >>= 1) part += __shfl_xor(part, d, 16);
    if (jj == 0) afa[(b * 32 + o2) * 128 + i] = part;
  }
}

// per-(b,n) MLP chain through scores softmax. grid 64, 128 threads = n.
__global__ __launch_bounds__(128, 1) void k4_mlp(
    const float* __restrict__ state, const float* __restrict__ f,
    const float* __restrict__ afa, const float* __restrict__ w_ia1,
    const float* __restrict__ b_ia1, const float* __restrict__ w_ia2,
    const float* __restrict__ b_ia2, const float* __restrict__ w_s1,
    const float* __restrict__ b_s1, const float* __restrict__ w_s2,
    const float* __restrict__ b_s2, const float* __restrict__ w_a1,
    const float* __restrict__ b_a1, const float* __restrict__ w_a2,
    const float* __restrict__ b_a2, const float* __restrict__ w_a3,
    const float* __restrict__ b_a3, float* __restrict__ smi,
    float* __restrict__ wts) {
  int b = blockIdx.x, n = threadIdx.x;
  __shared__ float so_s[128 * 33];
  __shared__ float gst[32];
  __shared__ float red[128];
  float x[32];
#pragma unroll 8
  for (int c = 0; c < 32; c++)
    x[c] = f[b * 4096 + c * 128 + n] + afa[b * 4096 + n * 32 + c];
  float h1[64];
  for (int o = 0; o < 64; o++) {
    float a = b_ia1[o];
#pragma unroll 8
    for (int c = 0; c < 32; c++) a += w_ia1[o * 32 + c] * x[c];
    h1[o] = fmaxf(a, 0.f);
  }
  float ia[38];
  for (int o = 0; o < 32; o++) {
    float a = b_ia2[o];
#pragma unroll 8
    for (int k = 0; k < 64; k++) a += w_ia2[o * 64 + k] * h1[k];
    ia[o] = a;
  }
#pragma unroll
  for (int k = 0; k < 6; k++) ia[32 + k] = state[(b * 128 + n) * 13 + k];
  float s1[64];
  for (int o = 0; o < 64; o++) {
    float a = b_s1[o];
#pragma unroll 2
    for (int k = 0; k < 38; k++) a += w_s1[o * 38 + k] * ia[k];
    s1[o] = fmaxf(a, 0.f);
  }
  float so[32];
  for (int o = 0; o < 32; o++) {
    float a = b_s2[o];
#pragma unroll 8
    for (int k = 0; k < 64; k++) a += w_s2[o * 64 + k] * s1[k];
    so[o] = a;
    so_s[n * 33 + o] = a;
  }
  __syncthreads();
  if (n < 32) {
    float a = 0.f;
    for (int m = 0; m < 128; m++) a += so_s[m * 33 + n];
    gst[n] = a * (1.f / 128.f);
  }
  __syncthreads();
#pragma unroll 8
  for (int k = 0; k < 32; k++) smi[b * 8192 + n * 64 + k] = so[k];
#pragma unroll 8
  for (int k = 0; k < 32; k++) smi[b * 8192 + n * 64 + 32 + k] = gst[k];
  float a1[64];
  for (int o = 0; o < 64; o++) {
    float a = b_a1[o];
#pragma unroll 8
    for (int k = 0; k < 32; k++) a += w_a1[o * 64 + k] * so[k];
#pragma unroll 8
    for (int k = 0; k < 32; k++) a += w_a1[o * 64 + 32 + k] * gst[k];
    a1[o] = fmaxf(a, 0.f);
  }
  float sc = b_a3[0];
  for (int o = 0; o < 32; o++) {
    float a = b_a2[o];
#pragma unroll 8
    for (int k = 0; k < 64; k++) a += w_a2[o * 64 + k] * a1[k];
    sc += w_a3[o] * fmaxf(a, 0.f);
  }
  float se = (sc != 0.f) ? expf(sc) : 0.f;
  red[n] = se;
  __syncthreads();
  for (int s = 64; s >= 1; s >>= 1) {
    if (n < s) red[n] += red[n + s];
    __syncthreads();
  }
  wts[b * 128 + n] = se / red[0];
}

// GRU r-gate: rh[b][c][n] = sigmoid(w_r . hx[:,n]) * h0[c][n]
__global__ __launch_bounds__(256) void k5a_r(
    const float* __restrict__ smi, const float* __restrict__ wts,
    const float* __restrict__ w_r, float* __restrict__ rh) {
  int cch = blockIdx.x, b = blockIdx.y, t = threadIdx.x;
  __shared__ float smi_s[128 * 65];
  __shared__ float wts_s[128];
  for (int idx = t; idx < 8192; idx += 256) {
    int n = idx >> 6, k = idx & 63;
    smi_s[n * 65 + k] = smi[b * 8192 + idx];
  }
  if (t < 128) wts_s[t] = wts[b * 128 + t];
  __syncthreads();
  int c = cch * 16 + (t >> 4), l = t & 15;
  float accs[8];
#pragma unroll
  for (int m = 0; m < 8; m++) accs[m] = 0.f;
  const float* wr = &w_r[c * 128];
  for (int k = 0; k < 64; k++) {
    float wv = wr[k];
#pragma unroll
    for (int m = 0; m < 8; m++) accs[m] += wv * smi_s[(l + 16 * m) * 65 + k];
  }
  for (int c2 = 0; c2 < 64; c2++) {
    float wv = wr[64 + c2];
    float g0 = wts_s[2 * c2], g1 = wts_s[2 * c2 + 1];
#pragma unroll
    for (int m = 0; m < 8; m++) {
      int nb = (m >> 2) & 1, nl = l + 16 * (m & 3);
      accs[m] += wv * ((nb ? g1 : g0) * smi_s[(2 * c2 + nb) * 65 + nl]);
    }
  }
#pragma unroll
  for (int m = 0; m < 8; m++) {
    int n = l + 16 * m;
    float r = 1.f / (1.f + expf(-accs[m]));
    rh[(b * 64 + c) * 128 + n] = r * smi_s[n * 65 + c];
  }
}

// GRU z, q, hn, mean over n.
__global__ __launch_bounds__(256) void k5b_gru(
    const float* __restrict__ smi, const float* __restrict__ wts,
    const float* __restrict__ rh, const float* __restrict__ w_z,
    const float* __restrict__ w_q, float* __restrict__ hnm) {
  int och = blockIdx.x, b = blockIdx.y, t = threadIdx.x;
  __shared__ float smi_s[128 * 65];
  __shared__ float wts_s[128];
  for (int idx = t; idx < 8192; idx += 256) {
    int n = idx >> 6, k = idx & 63;
    smi_s[n * 65 + k] = smi[b * 8192 + idx];
  }
  if (t < 128) wts_s[t] = wts[b * 128 + t];
  __syncthreads();
  int o = och * 16 + (t >> 4), l = t & 15;
  float az[8], aq[8];
#pragma unroll
  for (int m = 0; m < 8; m++) { az[m] = 0.f; aq[m] = 0.f; }
  const float* wz = &w_z[o * 128];
  const float* wq = &w_q[o * 128];
  const float* rhb = rh + b * 8192;
  for (int k = 0; k < 64; k++) {
    float wv = wz[k];
#pragma unroll
    for (int m = 0; m < 8; m++) az[m] += wv * smi_s[(l + 16 * m) * 65 + k];
  }
  for (int c = 0; c < 64; c++) {
    float wv = wq[c];
#pragma unroll
    for (int m = 0; m < 8; m++) aq[m] += wv * rhb[c * 128 + l + 16 * m];
  }
  for (int c2 = 0; c2 < 64; c2++) {
    float wvz = wz[64 + c2], wvq = wq[64 + c2];
    float g0 = wts_s[2 * c2], g1 = wts_s[2 * c2 + 1];
#pragma unroll
    for (int m = 0; m < 8; m++) {
      int nb = (m >> 2) & 1, nl = l + 16 * (m & 3);
      float gin = (nb ? g1 : g0) * smi_s[(2 * c2 + nb) * 65 + nl];
      az[m] += wvz * gin;
      aq[m] += wvq * gin;
    }
  }
  float part = 0.f;
#pragma unroll
  for (int m = 0; m < 8; m++) {
    int n = l + 16 * m;
    float z = 1.f / (1.f + expf(-az[m]));
    float q = tanhf(aq[m]);
    float h0 = smi_s[n * 65 + o];
    part += (1.f - z) * h0 + z * q;
  }
  for (int d = 8; d >= 1; d >>= 1) part += __shfl_xor(part, d, 16);
  if (l == 0) hnm[b * 64 + o] = part * (1.f / 128.f);
}

__global__ __launch_bounds__(128, 1) void k6_head(
    const float* __restrict__ state, const float* __restrict__ hnm,
    const float* __restrict__ w_m1, const float* __restrict__ b_m1,
    const float* __restrict__ w_m2, const float* __restrict__ b_m2,
    const float* __restrict__ w_m3, const float* __restrict__ b_m3,
    float* __restrict__ out) {
  int b = blockIdx.x, t = threadIdx.x;
  __shared__ float joint[70];
  __shared__ float m1s[128];
  __shared__ float red[64];
  if (t < 6) joint[t] = state[b * 1664 + t];
  if (t < 64) joint[6 + t] = hnm[b * 64 + t];
  __syncthreads();
  float a = b_m1[t];
#pragma unroll 2
  for (int k = 0; k < 70; k++) a += w_m1[t * 70 + k] * joint[k];
  m1s[t] = fmaxf(a, 0.f);
  __syncthreads();
  if (t < 64) {
    float a2 = b_m2[t];
#pragma unroll 8
    for (int k = 0; k < 128; k++) a2 += w_m2[t * 128 + k] * m1s[k];
    red[t] = fmaxf(a2, 0.f) * w_m3[t];
  }
  __syncthreads();
  for (int s = 32; s >= 1; s >>= 1) {
    if (t < s) red[t] += red[t + s];
    __syncthreads();
  }
  if (t == 0) out[b] = red[0] + b_m3[0];
}

extern "C" void kernel_launch(void* const* d_in, const int* in_sizes, int n_in,
                              void* d_out, int out_size, void* d_ws, size_t ws_size,
                              hipStream_t stream) {
  const float* state = (const float*)d_in[0];
  const float* w_in1 = (const float*)d_in[1];
  const float* b_in1 = (const float*)d_in[2];
  const float* w_in2 = (const float*)d_in[3];
  const float* b_in2 = (const float*)d_in[4];
  const float* w_c1  = (const float*)d_in[5];
  const float* b_c1  = (const float*)d_in[6];
  const float* w_c2  = (const float*)d_in[7];
  const float* b_c2  = (const float*)d_in[8];
  const float* w_ia1 = (const float*)d_in[9];
  const float* b_ia1 = (const float*)d_in[10];
  const float* w_ia2 = (const float*)d_in[11];
  const float* b_ia2 = (const float*)d_in[12];
  const float* w_s1  = (const float*)d_in[13];
  const float* b_s1  = (const float*)d_in[14];
  const float* w_s2  = (const float*)d_in[15];
  const float* b_s2  = (const float*)d_in[16];
  const float* w_a1  = (const float*)d_in[17];
  const float* b_a1  = (const float*)d_in[18];
  const float* w_a2  = (const float*)d_in[19];
  const float* b_a2  = (const float*)d_in[20];
  const float* w_a3  = (const float*)d_in[21];
  const float* b_a3  = (const float*)d_in[22];
  const float* w_z   = (const float*)d_in[23];
  const float* w_r   = (const float*)d_in[24];
  const float* w_q   = (const float*)d_in[25];
  const float* w_m1  = (const float*)d_in[26];
  const float* b_m1  = (const float*)d_in[27];
  const float* w_m2  = (const float*)d_in[28];
  const float* b_m2  = (const float*)d_in[29];
  const float* w_m3  = (const float*)d_in[30];
  const float* b_m3  = (const float*)d_in[31];
  float* ws   = (float*)d_ws;
  float* f_   = ws;
  float* R_   = ws + 262144;
  float* C_   = ws + 1835008;
  float* D_   = ws + 3407872;
  float* afa_ = ws + 6029312;
  float* smi_ = ws + 6291456;
  float* wts_ = ws + 6815744;
  float* rh_  = ws + 6823936;
  float* hnm_ = ws + 7348224;
  float* out  = (float*)d_out;

  k1_front<<<64, 128, 0, stream>>>(state, w_in1, b_in1, w_in2, b_in2, f_);
  k2_pre<<<dim3(64, 64), 128, 0, stream>>>(f_, w_c1, R_, C_, D_);
  k3_conv2<<<dim3(128, 64), 128, 0, stream>>>(f_, R_, C_, D_, b_c1, w_c2, b_c2, afa_);
  k4_mlp<<<64, 128, 0, stream>>>(state, f_, afa_, w_ia1, b_ia1, w_ia2, b_ia2,
                                 w_s1, b_s1, w_s2, b_s2, w_a1, b_a1, w_a2,
                                 b_a2, w_a3, b_a3, smi_, wts_);
  k5a_r<<<dim3(4, 64), 256, 0, stream>>>(smi_, wts_, w_r, rh_);
  k5b_gru<<<dim3(4, 64), 256, 0, stream>>>(smi_, wts_, rh_, w_z, w_q, hnm_);
  k6_head<<<64, 128, 0, stream>>>(state, hnm_, w_m1, b_m1, w_m2, b_m2, w_m3,
                                  b_m3, out);
}

// Round 2
// 981.721 us; speedup vs baseline: 2.6955x; 2.6955x over previous
//
#include <hip/hip_runtime.h>
#include <math.h>

// ValueNetwork forward, fp32.
// ws layout (floats):
//  f    [64][32][128]        @ 0        (262144)
//  R    [64][3][64][128]     @ 262144   (1572864)
//  C    [64][3][64][128]     @ 1835008  (1572864)
//  D    [64][64][128][5]     @ 3407872  (2621440)
//  afa  [64][32][128]        @ 6029312  (262144)
//  smi  [64][128][64]        @ 6291456  (524288)
//  wts  [64][128]            @ 6815744  (8192)
//  rh   [64][64][128]        @ 6823936  (524288)
//  hnm  [64][64]             @ 7348224  (4096)
//  w2p  [64][32][3][4]       @ 7352320  (24576)   prepacked conv2 weights
//  so   [64][128][32]        @ 7376896  (262144)
//  gst  [64][32]             @ 7639040  (2048)
//  se   [64][128]            @ 7641088  (8192)
// total 7649280 floats = 30.6 MB

// pack w_c2 [o2=32][cin=64][3][3] -> w2p [cc][o2][r][4] (x<3 valid, pad 0)
__global__ __launch_bounds__(256) void k0_pack(const float* __restrict__ w_c2,
                                               float* __restrict__ w2p) {
  for (int idx = threadIdx.x; idx < 24576; idx += 256) {
    int x = idx & 3, r = (idx >> 2) % 3, o2 = (idx / 12) & 31, cc = idx / 384;
    w2p[idx] = (x < 3) ? w_c2[o2 * 576 + cc * 9 + r * 3 + x] : 0.f;
  }
}

// front MLP: agents(7) -> 64 relu -> 32 relu, f[b][c][n]
// grid (b=64, nq=4), 128 thr = 32 rows x 4 lanes
__global__ __launch_bounds__(128) void k1_front(
    const float* __restrict__ state, const float* __restrict__ w_in1,
    const float* __restrict__ b_in1, const float* __restrict__ w_in2,
    const float* __restrict__ b_in2, float* __restrict__ f) {
  int b = blockIdx.x, nq = blockIdx.y, t = threadIdx.x;
  int row = t >> 2, lane = t & 3;
  int n = nq * 32 + row;
  __shared__ float hs[32][66];
  const float* st = state + (b * 128 + n) * 13 + 6;
  float a[7];
#pragma unroll
  for (int k = 0; k < 7; k++) a[k] = st[k];
  for (int oi = 0; oi < 16; oi++) {
    int o = lane * 16 + oi;
    float acc = b_in1[o];
#pragma unroll
    for (int k = 0; k < 7; k++) acc += w_in1[o * 7 + k] * a[k];
    hs[row][o] = fmaxf(acc, 0.f);
  }
  __syncthreads();
  for (int ci = 0; ci < 8; ci++) {
    int c = lane * 8 + ci;
    float acc = b_in2[c];
#pragma unroll 8
    for (int k = 0; k < 64; k++) acc += w_in2[c * 64 + k] * hs[row][k];
    f[(b * 32 + c) * 128 + n] = fmaxf(acc, 0.f);
  }
}

// conv1 low-rank precompute. grid (o=64, b=64), 128 threads = i.
__global__ __launch_bounds__(128) void k2_pre(
    const float* __restrict__ f, const float* __restrict__ w_c1,
    float* __restrict__ R, float* __restrict__ C, float* __restrict__ D) {
  int o = blockIdx.x, b = blockIdx.y, t = threadIdx.x;
  __shared__ float fL[32 * 128];
  __shared__ float w1s[32 * 9];
  __shared__ float wrow[32 * 9];
  __shared__ float wcol[32 * 9];
  for (int idx = t; idx < 4096; idx += 128) fL[idx] = f[b * 4096 + idx];
  for (int idx = t; idx < 288; idx += 128) w1s[idx] = w_c1[o * 288 + idx];
  __syncthreads();
  if (t < 32) {
    int c = t;
#pragma unroll
    for (int di = 0; di < 3; di++) {
      float w0 = w1s[c * 9 + di * 3 + 0], w1 = w1s[c * 9 + di * 3 + 1],
            w2 = w1s[c * 9 + di * 3 + 2];
      wrow[(c * 3 + di) * 3 + 0] = w1 + w2;
      wrow[(c * 3 + di) * 3 + 1] = w0 + w1 + w2;
      wrow[(c * 3 + di) * 3 + 2] = w0 + w1;
    }
#pragma unroll
    for (int dj = 0; dj < 3; dj++) {
      float w0 = w1s[c * 9 + 0 * 3 + dj], w1 = w1s[c * 9 + 1 * 3 + dj],
            w2 = w1s[c * 9 + 2 * 3 + dj];
      wcol[(c * 3 + dj) * 3 + 0] = w1 + w2;
      wcol[(c * 3 + dj) * 3 + 1] = w0 + w1 + w2;
      wcol[(c * 3 + dj) * 3 + 2] = w0 + w1;
    }
  }
  __syncthreads();
  int i = t;
  float r0 = 0, r1 = 0, r2 = 0, c0 = 0, c1 = 0, c2 = 0;
  float d0 = 0, d1 = 0, d2 = 0, d3 = 0, d4 = 0;
  for (int c = 0; c < 32; c++) {
    float fm = (i >= 1) ? fL[c * 128 + i - 1] : 0.f;
    float f0 = fL[c * 128 + i];
    float fp = (i < 127) ? fL[c * 128 + i + 1] : 0.f;
    const float* wr = &wrow[c * 9];
    r0 += fm * wr[0] + f0 * wr[3] + fp * wr[6];
    r1 += fm * wr[1] + f0 * wr[4] + fp * wr[7];
    r2 += fm * wr[2] + f0 * wr[5] + fp * wr[8];
    const float* wc = &wcol[c * 9];
    c0 += fm * wc[0] + f0 * wc[3] + fp * wc[6];
    c1 += fm * wc[1] + f0 * wc[4] + fp * wc[7];
    c2 += fm * wc[2] + f0 * wc[5] + fp * wc[8];
    const float* wp = &w1s[c * 9];
    d0 += fm * wp[2];
    d1 += fm * wp[1] + f0 * wp[5];
    d2 += fm * wp[0] + f0 * wp[4] + fp * wp[8];
    d3 += f0 * wp[3] + fp * wp[7];
    d4 += fp * wp[6];
  }
  R[((b * 3 + 0) * 64 + o) * 128 + i] = r0;
  R[((b * 3 + 1) * 64 + o) * 128 + i] = r1;
  R[((b * 3 + 2) * 64 + o) * 128 + i] = r2;
  C[((b * 3 + 0) * 64 + o) * 128 + i] = c0;
  C[((b * 3 + 1) * 64 + o) * 128 + i] = c1;
  C[((b * 3 + 2) * 64 + o) * 128 + i] = c2;
  float* dp = &D[((b * 64 + o) * 128 + i) * 5];
  dp[0] = d0; dp[1] = d1; dp[2] = d2; dp[3] = d3; dp[4] = d4;
}

// Fused conv2 + bias + softmax(j) + afa. grid (iblk=64, b=64), 256 threads.
// Block covers i0=2*iblk, i0+1. Per 128-thr half: jj=t&15 (8 j's), oo (4 o2's).
// 8 cc-chunks of 8; per chunk: smart per-row g rebuild into LDS.
__global__ __launch_bounds__(256, 4) void k3_conv2(
    const float* __restrict__ f, const float* __restrict__ R,
    const float* __restrict__ C, const float* __restrict__ D,
    const float* __restrict__ b_c1, const float* __restrict__ w2p,
    const float* __restrict__ b_c2, float* __restrict__ afa) {
  int iblk = blockIdx.x, b = blockIdx.y, t = threadIdx.x;
  int i0 = iblk * 2;
  int iloc = t >> 7;
  int tl = t & 127;
  int jj = tl & 15, oo = tl >> 4;
  int i = i0 + iloc;
  __shared__ float gs[4096];   // [rr4][ccL8][j128]
  __shared__ float w2s[3072];  // [ccL8][o2 32][r3][x4]
  float acc[4][8];
#pragma unroll
  for (int o = 0; o < 4; o++)
#pragma unroll
    for (int m = 0; m < 8; m++) acc[o][m] = 0.f;

  // build-phase thread mapping
  int combo = t >> 3;            // 0..31 = rr*8 + ccB
  int rr = combo >> 3, ccB = combo & 7;
  int lane8 = t & 7;
  int jlo = lane8 * 16;
  int ip = i0 - 1 + rr;
  bool rowok = (ip >= 0 && ip <= 127);
  int ic = (ip == 0) ? 0 : ((ip == 127) ? 2 : 1);

  for (int ck = 0; ck < 8; ck++) {
    int cc0 = ck * 8;
    // stage weights (contiguous chunk of prepacked w2p)
    {
      const float4* wsrc = (const float4*)(w2p + cc0 * 384);
      float4* wdst = (float4*)w2s;
      for (int idx = t; idx < 768; idx += 256) wdst[idx] = wsrc[idx];
    }
    // rebuild g rows: g[rr][ccB][j] = relu(conv1+bias), row-smart
    {
      float v[16];
      int cc = cc0 + ccB;
      float* dst = &gs[(rr * 8 + ccB) * 128 + jlo];
      if (!rowok) {
#pragma unroll
        for (int m = 0; m < 16; m++) v[m] = 0.f;
      } else {
        float bias = b_c1[cc];
        float base = R[((b * 3 + 1) * 64 + cc) * 128 + ip] + bias;
        const float* Crow = &C[((b * 3 + ic) * 64 + cc) * 128 + jlo];
        float4 c4[4];
#pragma unroll
        for (int q = 0; q < 4; q++) c4[q] = ((const float4*)Crow)[q];
#pragma unroll
        for (int m = 0; m < 16; m++) v[m] = base - ((const float*)c4)[m];
        if (lane8 == 0)
          v[0] = R[((b * 3 + 0) * 64 + cc) * 128 + ip] + bias - Crow[0];
        if (lane8 == 7)
          v[15] = R[((b * 3 + 2) * 64 + cc) * 128 + ip] + bias - Crow[15];
        const float* Dp = &D[((b * 64 + cc) * 128 + ip) * 5];
#pragma unroll
        for (int t5 = 0; t5 < 5; t5++) {
          int jb = ip - 2 + t5;
          if (jb >= jlo && jb < jlo + 16 && jb < 128 && jb >= 0)
            v[jb - jlo] += Dp[t5];
        }
#pragma unroll
        for (int m = 0; m < 16; m++) v[m] = fmaxf(v[m], 0.f);
      }
#pragma unroll
      for (int q = 0; q < 4; q++)
        ((float4*)dst)[q] = make_float4(v[q * 4], v[q * 4 + 1], v[q * 4 + 2],
                                        v[q * 4 + 3]);
    }
    __syncthreads();
    // GEMM on the chunk
    int j0 = jj * 8;
    for (int ccL = 0; ccL < 8; ++ccL) {
#pragma unroll
      for (int r = 0; r < 3; r++) {
        const float* gb = &gs[((iloc + r) * 8 + ccL) * 128];
        float win[10];
        win[0] = (j0 > 0) ? gb[j0 - 1] : 0.f;
        float4 ga = *(const float4*)&gb[j0];
        float4 gc = *(const float4*)&gb[j0 + 4];
        win[1] = ga.x; win[2] = ga.y; win[3] = ga.z; win[4] = ga.w;
        win[5] = gc.x; win[6] = gc.y; win[7] = gc.z; win[8] = gc.w;
        win[9] = (j0 + 8 < 128) ? gb[j0 + 8] : 0.f;
#pragma unroll
        for (int o = 0; o < 4; o++) {
          float4 wv = *(const float4*)&w2s[(ccL * 32 + (oo * 4 + o)) * 12 + r * 4];
#pragma unroll
          for (int m = 0; m < 8; m++)
            acc[o][m] += wv.x * win[m] + wv.y * win[m + 1] + wv.z * win[m + 2];
        }
      }
    }
    __syncthreads();
  }
  // epilogue: softmax over j + weighted pair reduction
  for (int idx = t; idx < 1024; idx += 256)
    ((float4*)gs)[idx] = ((const float4*)(f + b * 4096))[idx];
  __syncthreads();
  const float* fL = gs;
#pragma unroll
  for (int o = 0; o < 4; o++) {
    int o2 = oo * 4 + o;
    float bias = b_c2[o2];
    float mx = -3.0e38f;
#pragma unroll
    for (int m = 0; m < 8; m++) {
      acc[o][m] += bias;
      mx = fmaxf(mx, acc[o][m]);
    }
    for (int d = 8; d >= 1; d >>= 1) mx = fmaxf(mx, __shfl_xor(mx, d, 16));
    float s = 0.f;
#pragma unroll
    for (int m = 0; m < 8; m++) {
      float e = expf(acc[o][m] - mx);
      acc[o][m] = e;
      s += e;
    }
    for (int d = 8; d >= 1; d >>= 1) s += __shfl_xor(s, d, 16);
    float inv = 1.f / s;
    float fi = fL[o2 * 128 + i];
    float part = 0.f;
#pragma unroll
    for (int m = 0; m < 8; m++) {
      int j = jj * 8 + m;
      float w = acc[o][m] * inv;
      part += w * (fi - fL[o2 * 128 + j]);
      if (j == i) part += w * fi;
    }
    for (int d = 8; d >= 1; d >>= 1) part += __shfl_xor(part, d, 16);
    if (jj == 0) afa[(b * 32 + o2) * 128 + i] = part;
  }
}

// k4a: per (b,n): x -> h1 -> ia||self -> s1 -> so. grid 256 blocks, 256 thr.
// block = 32 rows x 8 lanes (row = t>>3, lane = t&7)
__global__ __launch_bounds__(256) void k4a_sort(
    const float* __restrict__ state, const float* __restrict__ f,
    const float* __restrict__ afa, const float* __restrict__ w_ia1,
    const float* __restrict__ b_ia1, const float* __restrict__ w_ia2,
    const float* __restrict__ b_ia2, const float* __restrict__ w_s1,
    const float* __restrict__ b_s1, const float* __restrict__ w_s2,
    const float* __restrict__ b_s2, float* __restrict__ so_g) {
  int blk = blockIdx.x;
  int b = blk >> 2, nq = blk & 3;
  int t = threadIdx.x, row = t >> 3, lane = t & 7;
  int n = nq * 32 + row;
  __shared__ float bufA[32][40];
  __shared__ float bufB[32][72];
  // stage 1: x = f + afa
  {
    int c0 = lane * 4;
    float4 av = *(const float4*)&afa[b * 4096 + n * 32 + c0];
    bufA[row][c0 + 0] = f[b * 4096 + (c0 + 0) * 128 + n] + av.x;
    bufA[row][c0 + 1] = f[b * 4096 + (c0 + 1) * 128 + n] + av.y;
    bufA[row][c0 + 2] = f[b * 4096 + (c0 + 2) * 128 + n] + av.z;
    bufA[row][c0 + 3] = f[b * 4096 + (c0 + 3) * 128 + n] + av.w;
  }
  __syncthreads();
  // stage 2: h1 (64 out, 32 in)
#pragma unroll
  for (int oi = 0; oi < 8; oi++) {
    int o = lane * 8 + oi;
    float a = b_ia1[o];
#pragma unroll 8
    for (int c = 0; c < 32; c++) a += w_ia1[o * 32 + c] * bufA[row][c];
    bufB[row][o] = fmaxf(a, 0.f);
  }
  __syncthreads();
  // stage 3: ia (32 out, 64 in) + self state
  {
    float r0[4];
#pragma unroll
    for (int oi = 0; oi < 4; oi++) {
      int o = lane * 4 + oi;
      float a = b_ia2[o];
#pragma unroll 8
      for (int k = 0; k < 64; k++) a += w_ia2[o * 64 + k] * bufB[row][k];
      r0[oi] = a;
    }
    __syncthreads();  // before overwriting bufA
#pragma unroll
    for (int oi = 0; oi < 4; oi++) bufA[row][lane * 4 + oi] = r0[oi];
    if (lane == 0) {
#pragma unroll
      for (int k = 0; k < 6; k++)
        bufA[row][32 + k] = state[(b * 128 + n) * 13 + k];
    }
  }
  __syncthreads();
  // stage 4: s1 (64 out, 38 in)
#pragma unroll
  for (int oi = 0; oi < 8; oi++) {
    int o = lane * 8 + oi;
    float a = b_s1[o];
#pragma unroll 2
    for (int k = 0; k < 38; k++) a += w_s1[o * 38 + k] * bufA[row][k];
    bufB[row][o] = fmaxf(a, 0.f);
  }
  __syncthreads();
  // stage 5: so (32 out, 64 in) -> global
#pragma unroll
  for (int oi = 0; oi < 4; oi++) {
    int o = lane * 4 + oi;
    float a = b_s2[o];
#pragma unroll 8
    for (int k = 0; k < 64; k++) a += w_s2[o * 64 + k] * bufB[row][k];
    so_g[(b * 128 + n) * 32 + o] = a;
  }
}

// k4b: gstate = mean over n. grid 64, 128 thr (c = t&31, part = t>>5)
__global__ __launch_bounds__(128) void k4b_gstate(const float* __restrict__ so_g,
                                                  float* __restrict__ gst) {
  int b = blockIdx.x, t = threadIdx.x;
  int c = t & 31, part = t >> 5;
  __shared__ float red[4][32];
  float a = 0.f;
  for (int nn = 0; nn < 32; nn++) a += so_g[(b * 128 + part * 32 + nn) * 32 + c];
  red[part][c] = a;
  __syncthreads();
  if (t < 32) gst[b * 32 + t] =
      (red[0][t] + red[1][t] + red[2][t] + red[3][t]) * (1.f / 128.f);
}

// k4c: smi write + a1 -> a2 -> score -> se. grid 256, 256 thr (32 rows x 8)
__global__ __launch_bounds__(256) void k4c_attn(
    const float* __restrict__ so_g, const float* __restrict__ gst,
    const float* __restrict__ w_a1, const float* __restrict__ b_a1,
    const float* __restrict__ w_a2, const float* __restrict__ b_a2,
    const float* __restrict__ w_a3, const float* __restrict__ b_a3,
    float* __restrict__ smi, float* __restrict__ se_g) {
  int blk = blockIdx.x;
  int b = blk >> 2, nq = blk & 3;
  int t = threadIdx.x, row = t >> 3, lane = t & 7;
  int n = nq * 32 + row;
  __shared__ float bufA[32][72];
  __shared__ float bufB[32][72];
  {
    int c0 = lane * 4;
    float4 sv = *(const float4*)&so_g[(b * 128 + n) * 32 + c0];
    float4 gv = *(const float4*)&gst[b * 32 + c0];
    *(float4*)&bufA[row][c0] = sv;
    *(float4*)&bufA[row][32 + c0] = gv;
    *(float4*)&smi[b * 8192 + n * 64 + c0] = sv;
    *(float4*)&smi[b * 8192 + n * 64 + 32 + c0] = gv;
  }
  __syncthreads();
#pragma unroll
  for (int oi = 0; oi < 8; oi++) {
    int o = lane * 8 + oi;
    float a = b_a1[o];
#pragma unroll 8
    for (int k = 0; k < 64; k++) a += w_a1[o * 64 + k] * bufA[row][k];
    bufB[row][o] = fmaxf(a, 0.f);
  }
  __syncthreads();
  float ps = 0.f;
#pragma unroll
  for (int oi = 0; oi < 4; oi++) {
    int o = lane * 4 + oi;
    float a = b_a2[o];
#pragma unroll 8
    for (int k = 0; k < 64; k++) a += w_a2[o * 64 + k] * bufB[row][k];
    ps += w_a3[o] * fmaxf(a, 0.f);
  }
  for (int d = 4; d >= 1; d >>= 1) ps += __shfl_xor(ps, d, 8);
  if (lane == 0) {
    float sc = ps + b_a3[0];
    se_g[b * 128 + n] = (sc != 0.f) ? expf(sc) : 0.f;
  }
}

// k4d: weights = se / sum(se). grid 64, 128 thr
__global__ __launch_bounds__(128) void k4d_wts(const float* __restrict__ se_g,
                                               float* __restrict__ wts) {
  int b = blockIdx.x, n = threadIdx.x;
  __shared__ float red[128];
  float se = se_g[b * 128 + n];
  red[n] = se;
  __syncthreads();
  for (int s = 64; s >= 1; s >>= 1) {
    if (n < s) red[n] += red[n + s];
    __syncthreads();
  }
  wts[b * 128 + n] = se / red[0];
}

// GRU r-gate
__global__ __launch_bounds__(256) void k5a_r(
    const float* __restrict__ smi, const float* __restrict__ wts,
    const float* __restrict__ w_r, float* __restrict__ rh) {
  int cch = blockIdx.x, b = blockIdx.y, t = threadIdx.x;
  __shared__ float smi_s[128 * 65];
  __shared__ float wts_s[128];
  for (int idx = t; idx < 8192; idx += 256) {
    int n = idx >> 6, k = idx & 63;
    smi_s[n * 65 + k] = smi[b * 8192 + idx];
  }
  if (t < 128) wts_s[t] = wts[b * 128 + t];
  __syncthreads();
  int c = cch * 16 + (t >> 4), l = t & 15;
  float accs[8];
#pragma unroll
  for (int m = 0; m < 8; m++) accs[m] = 0.f;
  const float* wr = &w_r[c * 128];
  for (int k = 0; k < 64; k++) {
    float wv = wr[k];
#pragma unroll
    for (int m = 0; m < 8; m++) accs[m] += wv * smi_s[(l + 16 * m) * 65 + k];
  }
  for (int c2 = 0; c2 < 64; c2++) {
    float wv = wr[64 + c2];
    float g0 = wts_s[2 * c2], g1 = wts_s[2 * c2 + 1];
#pragma unroll
    for (int m = 0; m < 8; m++) {
      int nb = (m >> 2) & 1, nl = l + 16 * (m & 3);
      accs[m] += wv * ((nb ? g1 : g0) * smi_s[(2 * c2 + nb) * 65 + nl]);
    }
  }
#pragma unroll
  for (int m = 0; m < 8; m++) {
    int n = l + 16 * m;
    float r = 1.f / (1.f + expf(-accs[m]));
    rh[(b * 64 + c) * 128 + n] = r * smi_s[n * 65 + c];
  }
}

// GRU z, q, hn, mean over n
__global__ __launch_bounds__(256) void k5b_gru(
    const float* __restrict__ smi, const float* __restrict__ wts,
    const float* __restrict__ rh, const float* __restrict__ w_z,
    const float* __restrict__ w_q, float* __restrict__ hnm) {
  int och = blockIdx.x, b = blockIdx.y, t = threadIdx.x;
  __shared__ float smi_s[128 * 65];
  __shared__ float wts_s[128];
  for (int idx = t; idx < 8192; idx += 256) {
    int n = idx >> 6, k = idx & 63;
    smi_s[n * 65 + k] = smi[b * 8192 + idx];
  }
  if (t < 128) wts_s[t] = wts[b * 128 + t];
  __syncthreads();
  int o = och * 16 + (t >> 4), l = t & 15;
  float az[8], aq[8];
#pragma unroll
  for (int m = 0; m < 8; m++) { az[m] = 0.f; aq[m] = 0.f; }
  const float* wz = &w_z[o * 128];
  const float* wq = &w_q[o * 128];
  const float* rhb = rh + b * 8192;
  for (int k = 0; k < 64; k++) {
    float wv = wz[k];
#pragma unroll
    for (int m = 0; m < 8; m++) az[m] += wv * smi_s[(l + 16 * m) * 65 + k];
  }
  for (int c = 0; c < 64; c++) {
    float wv = wq[c];
#pragma unroll
    for (int m = 0; m < 8; m++) aq[m] += wv * rhb[c * 128 + l + 16 * m];
  }
  for (int c2 = 0; c2 < 64; c2++) {
    float wvz = wz[64 + c2], wvq = wq[64 + c2];
    float g0 = wts_s[2 * c2], g1 = wts_s[2 * c2 + 1];
#pragma unroll
    for (int m = 0; m < 8; m++) {
      int nb = (m >> 2) & 1, nl = l + 16 * (m & 3);
      float gin = (nb ? g1 : g0) * smi_s[(2 * c2 + nb) * 65 + nl];
      az[m] += wvz * gin;
      aq[m] += wvq * gin;
    }
  }
  float part = 0.f;
#pragma unroll
  for (int m = 0; m < 8; m++) {
    int n = l + 16 * m;
    float z = 1.f / (1.f + expf(-az[m]));
    float q = tanhf(aq[m]);
    float h0 = smi_s[n * 65 + o];
    part += (1.f - z) * h0 + z * q;
  }
  for (int d = 8; d >= 1; d >>= 1) part += __shfl_xor(part, d, 16);
  if (l == 0) hnm[b * 64 + o] = part * (1.f / 128.f);
}

__global__ __launch_bounds__(128, 1) void k6_head(
    const float* __restrict__ state, const float* __restrict__ hnm,
    const float* __restrict__ w_m1, const float* __restrict__ b_m1,
    const float* __restrict__ w_m2, const float* __restrict__ b_m2,
    const float* __restrict__ w_m3, const float* __restrict__ b_m3,
    float* __restrict__ out) {
  int b = blockIdx.x, t = threadIdx.x;
  __shared__ float joint[70];
  __shared__ float m1s[128];
  __shared__ float red[64];
  if (t < 6) joint[t] = state[b * 1664 + t];
  if (t < 64) joint[6 + t] = hnm[b * 64 + t];
  __syncthreads();
  float a = b_m1[t];
#pragma unroll 2
  for (int k = 0; k < 70; k++) a += w_m1[t * 70 + k] * joint[k];
  m1s[t] = fmaxf(a, 0.f);
  __syncthreads();
  if (t < 64) {
    float a2 = b_m2[t];
#pragma unroll 8
    for (int k = 0; k < 128; k++) a2 += w_m2[t * 128 + k] * m1s[k];
    red[t] = fmaxf(a2, 0.f) * w_m3[t];
  }
  __syncthreads();
  for (int s = 32; s >= 1; s >>= 1) {
    if (t < s) red[t] += red[t + s];
    __syncthreads();
  }
  if (t == 0) out[b] = red[0] + b_m3[0];
}

extern "C" void kernel_launch(void* const* d_in, const int* in_sizes, int n_in,
                              void* d_out, int out_size, void* d_ws, size_t ws_size,
                              hipStream_t stream) {
  const float* state = (const float*)d_in[0];
  const float* w_in1 = (const float*)d_in[1];
  const float* b_in1 = (const float*)d_in[2];
  const float* w_in2 = (const float*)d_in[3];
  const float* b_in2 = (const float*)d_in[4];
  const float* w_c1  = (const float*)d_in[5];
  const float* b_c1  = (const float*)d_in[6];
  const float* w_c2  = (const float*)d_in[7];
  const float* b_c2  = (const float*)d_in[8];
  const float* w_ia1 = (const float*)d_in[9];
  const float* b_ia1 = (const float*)d_in[10];
  const float* w_ia2 = (const float*)d_in[11];
  const float* b_ia2 = (const float*)d_in[12];
  const float* w_s1  = (const float*)d_in[13];
  const float* b_s1  = (const float*)d_in[14];
  const float* w_s2  = (const float*)d_in[15];
  const float* b_s2  = (const float*)d_in[16];
  const float* w_a1  = (const float*)d_in[17];
  const float* b_a1  = (const float*)d_in[18];
  const float* w_a2  = (const float*)d_in[19];
  const float* b_a2  = (const float*)d_in[20];
  const float* w_a3  = (const float*)d_in[21];
  const float* b_a3  = (const float*)d_in[22];
  const float* w_z   = (const float*)d_in[23];
  const float* w_r   = (const float*)d_in[24];
  const float* w_q   = (const float*)d_in[25];
  const float* w_m1  = (const float*)d_in[26];
  const float* b_m1  = (const float*)d_in[27];
  const float* w_m2  = (const float*)d_in[28];
  const float* b_m2  = (const float*)d_in[29];
  const float* w_m3  = (const float*)d_in[30];
  const float* b_m3  = (const float*)d_in[31];
  float* ws    = (float*)d_ws;
  float* f_    = ws;
  float* R_    = ws + 262144;
  float* C_    = ws + 1835008;
  float* D_    = ws + 3407872;
  float* afa_  = ws + 6029312;
  float* smi_  = ws + 6291456;
  float* wts_  = ws + 6815744;
  float* rh_   = ws + 6823936;
  float* hnm_  = ws + 7348224;
  float* w2p_  = ws + 7352320;
  float* so_   = ws + 7376896;
  float* gst_  = ws + 7639040;
  float* se_   = ws + 7641088;
  float* out   = (float*)d_out;

  k0_pack<<<1, 256, 0, stream>>>(w_c2, w2p_);
  k1_front<<<dim3(64, 4), 128, 0, stream>>>(state, w_in1, b_in1, w_in2, b_in2, f_);
  k2_pre<<<dim3(64, 64), 128, 0, stream>>>(f_, w_c1, R_, C_, D_);
  k3_conv2<<<dim3(64, 64), 256, 0, stream>>>(f_, R_, C_, D_, b_c1, w2p_, b_c2, afa_);
  k4a_sort<<<256, 256, 0, stream>>>(state, f_, afa_, w_ia1, b_ia1, w_ia2, b_ia2,
                                    w_s1, b_s1, w_s2, b_s2, so_);
  k4b_gstate<<<64, 128, 0, stream>>>(so_, gst_);
  k4c_attn<<<256, 256, 0, stream>>>(so_, gst_, w_a1, b_a1, w_a2, b_a2, w_a3,
                                    b_a3, smi_, se_);
  k4d_wts<<<64, 128, 0, stream>>>(se_, wts_);
  k5a_r<<<dim3(4, 64), 256, 0, stream>>>(smi_, wts_, w_r, rh_);
  k5b_gru<<<dim3(4, 64), 256, 0, stream>>>(smi_, wts_, rh_, w_z, w_q, hnm_);
  k6_head<<<64, 128, 0, stream>>>(state, hnm_, w_m1, b_m1, w_m2, b_m2, w_m3,
                                  b_m3, out);
}

// Round 3
// 837.061 us; speedup vs baseline: 3.1614x; 1.1728x over previous
//
#include <hip/hip_runtime.h>
#include <math.h>

// ValueNetwork forward, fp32.
// ws layout (floats):
//  f    [64][32][128]        @ 0        (262144)
//  R    [64][3][64][128]     @ 262144   (1572864)
//  C    [64][3][64][128]     @ 1835008  (1572864)
//  D    [64][64][128][5]     @ 3407872  (2621440)
//  afa  [64][32][128]        @ 6029312  (262144)
//  smi  [64][128][64]        @ 6291456  (524288)
//  wts  [64][128]            @ 6815744  (8192)
//  rh   [64][64][128]        @ 6823936  (524288)
//  hnm  [64][64]             @ 7348224  (4096)
//  w2p  [64][32][3][4]       @ 7352320  (24576)   prepacked conv2 weights
//  so   [64][128][32]        @ 7376896  (262144)
//  gst  [64][32]             @ 7639040  (2048)
//  se   [64][128]            @ 7641088  (8192)
// total 7649280 floats = 30.6 MB

// pack w_c2 [o2=32][cin=64][3][3] -> w2p [cc][o2][r][4] (x<3 valid, pad 0)
__global__ __launch_bounds__(256) void k0_pack(const float* __restrict__ w_c2,
                                               float* __restrict__ w2p) {
  for (int idx = threadIdx.x; idx < 24576; idx += 256) {
    int x = idx & 3, r = (idx >> 2) % 3, o2 = (idx / 12) & 31, cc = idx / 384;
    w2p[idx] = (x < 3) ? w_c2[o2 * 576 + cc * 9 + r * 3 + x] : 0.f;
  }
}

// front MLP: agents(7) -> 64 relu -> 32 relu, f[b][c][n]
__global__ __launch_bounds__(128) void k1_front(
    const float* __restrict__ state, const float* __restrict__ w_in1,
    const float* __restrict__ b_in1, const float* __restrict__ w_in2,
    const float* __restrict__ b_in2, float* __restrict__ f) {
  int b = blockIdx.x, nq = blockIdx.y, t = threadIdx.x;
  int row = t >> 2, lane = t & 3;
  int n = nq * 32 + row;
  __shared__ float hs[32][66];
  const float* st = state + (b * 128 + n) * 13 + 6;
  float a[7];
#pragma unroll
  for (int k = 0; k < 7; k++) a[k] = st[k];
  for (int oi = 0; oi < 16; oi++) {
    int o = lane * 16 + oi;
    float acc = b_in1[o];
#pragma unroll
    for (int k = 0; k < 7; k++) acc += w_in1[o * 7 + k] * a[k];
    hs[row][o] = fmaxf(acc, 0.f);
  }
  __syncthreads();
  for (int ci = 0; ci < 8; ci++) {
    int c = lane * 8 + ci;
    float acc = b_in2[c];
#pragma unroll 8
    for (int k = 0; k < 64; k++) acc += w_in2[c * 64 + k] * hs[row][k];
    f[(b * 32 + c) * 128 + n] = fmaxf(acc, 0.f);
  }
}

// conv1 low-rank precompute. grid (o=64, b=64), 128 threads = i.
__global__ __launch_bounds__(128) void k2_pre(
    const float* __restrict__ f, const float* __restrict__ w_c1,
    float* __restrict__ R, float* __restrict__ C, float* __restrict__ D) {
  int o = blockIdx.x, b = blockIdx.y, t = threadIdx.x;
  __shared__ float fL[32 * 128];
  __shared__ float w1s[32 * 9];
  __shared__ float wrow[32 * 9];
  __shared__ float wcol[32 * 9];
  for (int idx = t; idx < 4096; idx += 128) fL[idx] = f[b * 4096 + idx];
  for (int idx = t; idx < 288; idx += 128) w1s[idx] = w_c1[o * 288 + idx];
  __syncthreads();
  if (t < 32) {
    int c = t;
#pragma unroll
    for (int di = 0; di < 3; di++) {
      float w0 = w1s[c * 9 + di * 3 + 0], w1 = w1s[c * 9 + di * 3 + 1],
            w2 = w1s[c * 9 + di * 3 + 2];
      wrow[(c * 3 + di) * 3 + 0] = w1 + w2;
      wrow[(c * 3 + di) * 3 + 1] = w0 + w1 + w2;
      wrow[(c * 3 + di) * 3 + 2] = w0 + w1;
    }
#pragma unroll
    for (int dj = 0; dj < 3; dj++) {
      float w0 = w1s[c * 9 + 0 * 3 + dj], w1 = w1s[c * 9 + 1 * 3 + dj],
            w2 = w1s[c * 9 + 2 * 3 + dj];
      wcol[(c * 3 + dj) * 3 + 0] = w1 + w2;
      wcol[(c * 3 + dj) * 3 + 1] = w0 + w1 + w2;
      wcol[(c * 3 + dj) * 3 + 2] = w0 + w1;
    }
  }
  __syncthreads();
  int i = t;
  float r0 = 0, r1 = 0, r2 = 0, c0 = 0, c1 = 0, c2 = 0;
  float d0 = 0, d1 = 0, d2 = 0, d3 = 0, d4 = 0;
  for (int c = 0; c < 32; c++) {
    float fm = (i >= 1) ? fL[c * 128 + i - 1] : 0.f;
    float f0 = fL[c * 128 + i];
    float fp = (i < 127) ? fL[c * 128 + i + 1] : 0.f;
    const float* wr = &wrow[c * 9];
    r0 += fm * wr[0] + f0 * wr[3] + fp * wr[6];
    r1 += fm * wr[1] + f0 * wr[4] + fp * wr[7];
    r2 += fm * wr[2] + f0 * wr[5] + fp * wr[8];
    const float* wc = &wcol[c * 9];
    c0 += fm * wc[0] + f0 * wc[3] + fp * wc[6];
    c1 += fm * wc[1] + f0 * wc[4] + fp * wc[7];
    c2 += fm * wc[2] + f0 * wc[5] + fp * wc[8];
    const float* wp = &w1s[c * 9];
    d0 += fm * wp[2];
    d1 += fm * wp[1] + f0 * wp[5];
    d2 += fm * wp[0] + f0 * wp[4] + fp * wp[8];
    d3 += f0 * wp[3] + fp * wp[7];
    d4 += fp * wp[6];
  }
  R[((b * 3 + 0) * 64 + o) * 128 + i] = r0;
  R[((b * 3 + 1) * 64 + o) * 128 + i] = r1;
  R[((b * 3 + 2) * 64 + o) * 128 + i] = r2;
  C[((b * 3 + 0) * 64 + o) * 128 + i] = c0;
  C[((b * 3 + 1) * 64 + o) * 128 + i] = c1;
  C[((b * 3 + 2) * 64 + o) * 128 + i] = c2;
  float* dp = &D[((b * 64 + o) * 128 + i) * 5];
  dp[0] = d0; dp[1] = d1; dp[2] = d2; dp[3] = d3; dp[4] = d4;
}

// Fused conv2 + bias + softmax(j) + afa. grid (iblk=64, b=64), 256 threads.
// gs row layout (152 floats): [guard 4][seg0 32][gap 4][seg1 32][gap 4]
// [seg2 32][gap 4][seg3 32][tail 8-ish]; physical(j) = j + 4 + 4*(j>>5).
// Guards/gaps are zeroed once; boundary taps read them unconditionally.
#define GS_RS 152
__global__ __launch_bounds__(256, 4) void k3_conv2(
    const float* __restrict__ f, const float* __restrict__ R,
    const float* __restrict__ C, const float* __restrict__ D,
    const float* __restrict__ b_c1, const float* __restrict__ w2p,
    const float* __restrict__ b_c2, float* __restrict__ afa) {
  int iblk = blockIdx.x, b = blockIdx.y, t = threadIdx.x;
  int i0 = iblk * 2;
  int iloc = t >> 7;
  int tl = t & 127;
  int jj = tl & 15, oo = tl >> 4;
  int i = i0 + iloc;
  __shared__ float gs[32 * GS_RS];  // 19456 floats? no: 4864 floats
  __shared__ float w2s[3072];       // [ccL8][o2 32][r3][x4]
  float acc[4][8];
#pragma unroll
  for (int o = 0; o < 4; o++)
#pragma unroll
    for (int m = 0; m < 8; m++) acc[o][m] = 0.f;

  // zero-init gs (guards/gaps must be 0)
  for (int idx = t; idx < 32 * GS_RS; idx += 256) gs[idx] = 0.f;

  // per-thread constant physical offsets for the j-window
  int j0 = jj * 8;
  int p0 = j0 + 4 + 4 * (j0 >> 5);
  int pm1 = (j0 == 0) ? 3 : (((j0 & 31) == 0) ? (p0 - 5) : (p0 - 1));
  int pp8 = ((j0 & 31) == 24) ? (p0 + 12) : (p0 + 8);

  // build-phase thread mapping
  int combo = t >> 3;  // 0..31 = rr*8 + ccB
  int rr = combo >> 3, ccB = combo & 7;
  int lane8 = t & 7;
  int jlo = lane8 * 16;
  int pjlo = jlo + 4 + 4 * (jlo >> 5);
  int ip = i0 - 1 + rr;
  bool rowok = (ip >= 0 && ip <= 127);
  int ic = (ip == 0) ? 0 : ((ip == 127) ? 2 : 1);
  __syncthreads();

  for (int ck = 0; ck < 8; ck++) {
    int cc0 = ck * 8;
    // stage weights (contiguous chunk of prepacked w2p)
    {
      const float4* wsrc = (const float4*)(w2p + cc0 * 384);
      float4* wdst = (float4*)w2s;
      for (int idx = t; idx < 768; idx += 256) wdst[idx] = wsrc[idx];
    }
    // rebuild g rows: g[rr][ccB][j] = relu(conv1+bias), row-smart
    if (rowok) {
      float v[16];
      int cc = cc0 + ccB;
      float* dst = &gs[(rr * 8 + ccB) * GS_RS + pjlo];
      float bias = b_c1[cc];
      float base = R[((b * 3 + 1) * 64 + cc) * 128 + ip] + bias;
      const float* Crow = &C[((b * 3 + ic) * 64 + cc) * 128 + jlo];
      float4 c4[4];
#pragma unroll
      for (int q = 0; q < 4; q++) c4[q] = ((const float4*)Crow)[q];
#pragma unroll
      for (int m = 0; m < 16; m++) v[m] = base - ((const float*)c4)[m];
      if (lane8 == 0)
        v[0] = R[((b * 3 + 0) * 64 + cc) * 128 + ip] + bias - Crow[0];
      if (lane8 == 7)
        v[15] = R[((b * 3 + 2) * 64 + cc) * 128 + ip] + bias - Crow[15];
      const float* Dp = &D[((b * 64 + cc) * 128 + ip) * 5];
#pragma unroll
      for (int t5 = 0; t5 < 5; t5++) {
        int jb = ip - 2 + t5;
        if (jb >= jlo && jb < jlo + 16 && jb < 128 && jb >= 0)
          v[jb - jlo] += Dp[t5];
      }
#pragma unroll
      for (int m = 0; m < 16; m++) v[m] = fmaxf(v[m], 0.f);
#pragma unroll
      for (int q = 0; q < 4; q++)
        ((float4*)dst)[q] = make_float4(v[q * 4], v[q * 4 + 1], v[q * 4 + 2],
                                        v[q * 4 + 3]);
    }
    __syncthreads();
    // GEMM on the chunk: pure fma inner loop
    for (int ccL = 0; ccL < 8; ++ccL) {
#pragma unroll
      for (int r = 0; r < 3; r++) {
        const float* gb = &gs[((iloc + r) * 8 + ccL) * GS_RS];
        float win[10];
        win[0] = gb[pm1];
        *(float4*)&win[1] = *(const float4*)&gb[p0];
        *(float4*)&win[5] = *(const float4*)&gb[p0 + 4];
        win[9] = gb[pp8];
#pragma unroll
        for (int o = 0; o < 4; o++) {
          float4 wv = *(const float4*)&w2s[(ccL * 32 + (oo * 4 + o)) * 12 + r * 4];
#pragma unroll
          for (int m = 0; m < 8; m++) {
            float a = acc[o][m];
            a = fmaf(wv.x, win[m], a);
            a = fmaf(wv.y, win[m + 1], a);
            a = fmaf(wv.z, win[m + 2], a);
            acc[o][m] = a;
          }
        }
      }
    }
    __syncthreads();
  }
  // epilogue: softmax over j + weighted pair reduction
  for (int idx = t; idx < 1024; idx += 256)
    ((float4*)gs)[idx] = ((const float4*)(f + b * 4096))[idx];
  __syncthreads();
  const float* fL = gs;
#pragma unroll
  for (int o = 0; o < 4; o++) {
    int o2 = oo * 4 + o;
    float bias = b_c2[o2];
    float mx = -3.0e38f;
#pragma unroll
    for (int m = 0; m < 8; m++) {
      acc[o][m] += bias;
      mx = fmaxf(mx, acc[o][m]);
    }
    for (int d = 8; d >= 1; d >>= 1) mx = fmaxf(mx, __shfl_xor(mx, d, 16));
    float s = 0.f;
#pragma unroll
    for (int m = 0; m < 8; m++) {
      float e = expf(acc[o][m] - mx);
      acc[o][m] = e;
      s += e;
    }
    for (int d = 8; d >= 1; d >>= 1) s += __shfl_xor(s, d, 16);
    float inv = 1.f / s;
    float fi = fL[o2 * 128 + i];
    float part = 0.f;
#pragma unroll
    for (int m = 0; m < 8; m++) {
      int j = jj * 8 + m;
      float w = acc[o][m] * inv;
      part += w * (fi - fL[o2 * 128 + j]);
      if (j == i) part += w * fi;
    }
    for (int d = 8; d >= 1; d >>= 1) part += __shfl_xor(part, d, 16);
    if (jj == 0) afa[(b * 32 + o2) * 128 + i] = part;
  }
}

// k4a: per (b,n): x -> h1 -> ia||self -> s1 -> so. grid 256 blocks, 256 thr.
__global__ __launch_bounds__(256) void k4a_sort(
    const float* __restrict__ state, const float* __restrict__ f,
    const float* __restrict__ afa, const float* __restrict__ w_ia1,
    const float* __restrict__ b_ia1, const float* __restrict__ w_ia2,
    const float* __restrict__ b_ia2, const float* __restrict__ w_s1,
    const float* __restrict__ b_s1, const float* __restrict__ w_s2,
    const float* __restrict__ b_s2, float* __restrict__ so_g) {
  int blk = blockIdx.x;
  int b = blk >> 2, nq = blk & 3;
  int t = threadIdx.x, row = t >> 3, lane = t & 7;
  int n = nq * 32 + row;
  __shared__ float bufA[32][40];
  __shared__ float bufB[32][72];
  {
    int c0 = lane * 4;
    float4 av = *(const float4*)&afa[b * 4096 + n * 32 + c0];
    bufA[row][c0 + 0] = f[b * 4096 + (c0 + 0) * 128 + n] + av.x;
    bufA[row][c0 + 1] = f[b * 4096 + (c0 + 1) * 128 + n] + av.y;
    bufA[row][c0 + 2] = f[b * 4096 + (c0 + 2) * 128 + n] + av.z;
    bufA[row][c0 + 3] = f[b * 4096 + (c0 + 3) * 128 + n] + av.w;
  }
  __syncthreads();
#pragma unroll
  for (int oi = 0; oi < 8; oi++) {
    int o = lane * 8 + oi;
    float a = b_ia1[o];
#pragma unroll 8
    for (int c = 0; c < 32; c++) a += w_ia1[o * 32 + c] * bufA[row][c];
    bufB[row][o] = fmaxf(a, 0.f);
  }
  __syncthreads();
  {
    float r0[4];
#pragma unroll
    for (int oi = 0; oi < 4; oi++) {
      int o = lane * 4 + oi;
      float a = b_ia2[o];
#pragma unroll 8
      for (int k = 0; k < 64; k++) a += w_ia2[o * 64 + k] * bufB[row][k];
      r0[oi] = a;
    }
    __syncthreads();
#pragma unroll
    for (int oi = 0; oi < 4; oi++) bufA[row][lane * 4 + oi] = r0[oi];
    if (lane == 0) {
#pragma unroll
      for (int k = 0; k < 6; k++)
        bufA[row][32 + k] = state[(b * 128 + n) * 13 + k];
    }
  }
  __syncthreads();
#pragma unroll
  for (int oi = 0; oi < 8; oi++) {
    int o = lane * 8 + oi;
    float a = b_s1[o];
#pragma unroll 2
    for (int k = 0; k < 38; k++) a += w_s1[o * 38 + k] * bufA[row][k];
    bufB[row][o] = fmaxf(a, 0.f);
  }
  __syncthreads();
#pragma unroll
  for (int oi = 0; oi < 4; oi++) {
    int o = lane * 4 + oi;
    float a = b_s2[o];
#pragma unroll 8
    for (int k = 0; k < 64; k++) a += w_s2[o * 64 + k] * bufB[row][k];
    so_g[(b * 128 + n) * 32 + o] = a;
  }
}

__global__ __launch_bounds__(128) void k4b_gstate(const float* __restrict__ so_g,
                                                  float* __restrict__ gst) {
  int b = blockIdx.x, t = threadIdx.x;
  int c = t & 31, part = t >> 5;
  __shared__ float red[4][32];
  float a = 0.f;
  for (int nn = 0; nn < 32; nn++) a += so_g[(b * 128 + part * 32 + nn) * 32 + c];
  red[part][c] = a;
  __syncthreads();
  if (t < 32) gst[b * 32 + t] =
      (red[0][t] + red[1][t] + red[2][t] + red[3][t]) * (1.f / 128.f);
}

__global__ __launch_bounds__(256) void k4c_attn(
    const float* __restrict__ so_g, const float* __restrict__ gst,
    const float* __restrict__ w_a1, const float* __restrict__ b_a1,
    const float* __restrict__ w_a2, const float* __restrict__ b_a2,
    const float* __restrict__ w_a3, const float* __restrict__ b_a3,
    float* __restrict__ smi, float* __restrict__ se_g) {
  int blk = blockIdx.x;
  int b = blk >> 2, nq = blk & 3;
  int t = threadIdx.x, row = t >> 3, lane = t & 7;
  int n = nq * 32 + row;
  __shared__ float bufA[32][72];
  __shared__ float bufB[32][72];
  {
    int c0 = lane * 4;
    float4 sv = *(const float4*)&so_g[(b * 128 + n) * 32 + c0];
    float4 gv = *(const float4*)&gst[b * 32 + c0];
    *(float4*)&bufA[row][c0] = sv;
    *(float4*)&bufA[row][32 + c0] = gv;
    *(float4*)&smi[b * 8192 + n * 64 + c0] = sv;
    *(float4*)&smi[b * 8192 + n * 64 + 32 + c0] = gv;
  }
  __syncthreads();
#pragma unroll
  for (int oi = 0; oi < 8; oi++) {
    int o = lane * 8 + oi;
    float a = b_a1[o];
#pragma unroll 8
    for (int k = 0; k < 64; k++) a += w_a1[o * 64 + k] * bufA[row][k];
    bufB[row][o] = fmaxf(a, 0.f);
  }
  __syncthreads();
  float ps = 0.f;
#pragma unroll
  for (int oi = 0; oi < 4; oi++) {
    int o = lane * 4 + oi;
    float a = b_a2[o];
#pragma unroll 8
    for (int k = 0; k < 64; k++) a += w_a2[o * 64 + k] * bufB[row][k];
    ps += w_a3[o] * fmaxf(a, 0.f);
  }
  for (int d = 4; d >= 1; d >>= 1) ps += __shfl_xor(ps, d, 8);
  if (lane == 0) {
    float sc = ps + b_a3[0];
    se_g[b * 128 + n] = (sc != 0.f) ? expf(sc) : 0.f;
  }
}

__global__ __launch_bounds__(128) void k4d_wts(const float* __restrict__ se_g,
                                               float* __restrict__ wts) {
  int b = blockIdx.x, n = threadIdx.x;
  __shared__ float red[128];
  float se = se_g[b * 128 + n];
  red[n] = se;
  __syncthreads();
  for (int s = 64; s >= 1; s >>= 1) {
    if (n < s) red[n] += red[n + s];
    __syncthreads();
  }
  wts[b * 128 + n] = se / red[0];
}

// GRU r-gate
__global__ __launch_bounds__(256) void k5a_r(
    const float* __restrict__ smi, const float* __restrict__ wts,
    const float* __restrict__ w_r, float* __restrict__ rh) {
  int cch = blockIdx.x, b = blockIdx.y, t = threadIdx.x;
  __shared__ float smi_s[128 * 65];
  __shared__ float wts_s[128];
  for (int idx = t; idx < 8192; idx += 256) {
    int n = idx >> 6, k = idx & 63;
    smi_s[n * 65 + k] = smi[b * 8192 + idx];
  }
  if (t < 128) wts_s[t] = wts[b * 128 + t];
  __syncthreads();
  int c = cch * 16 + (t >> 4), l = t & 15;
  float accs[8];
#pragma unroll
  for (int m = 0; m < 8; m++) accs[m] = 0.f;
  const float* wr = &w_r[c * 128];
  for (int k = 0; k < 64; k++) {
    float wv = wr[k];
#pragma unroll
    for (int m = 0; m < 8; m++) accs[m] += wv * smi_s[(l + 16 * m) * 65 + k];
  }
  for (int c2 = 0; c2 < 64; c2++) {
    float wv = wr[64 + c2];
    float g0 = wts_s[2 * c2], g1 = wts_s[2 * c2 + 1];
#pragma unroll
    for (int m = 0; m < 8; m++) {
      int nb = (m >> 2) & 1, nl = l + 16 * (m & 3);
      accs[m] += wv * ((nb ? g1 : g0) * smi_s[(2 * c2 + nb) * 65 + nl]);
    }
  }
#pragma unroll
  for (int m = 0; m < 8; m++) {
    int n = l + 16 * m;
    float r = 1.f / (1.f + expf(-accs[m]));
    rh[(b * 64 + c) * 128 + n] = r * smi_s[n * 65 + c];
  }
}

// GRU z, q, hn, mean over n
__global__ __launch_bounds__(256) void k5b_gru(
    const float* __restrict__ smi, const float* __restrict__ wts,
    const float* __restrict__ rh, const float* __restrict__ w_z,
    const float* __restrict__ w_q, float* __restrict__ hnm) {
  int och = blockIdx.x, b = blockIdx.y, t = threadIdx.x;
  __shared__ float smi_s[128 * 65];
  __shared__ float wts_s[128];
  for (int idx = t; idx < 8192; idx += 256) {
    int n = idx >> 6, k = idx & 63;
    smi_s[n * 65 + k] = smi[b * 8192 + idx];
  }
  if (t < 128) wts_s[t] = wts[b * 128 + t];
  __syncthreads();
  int o = och * 16 + (t >> 4), l = t & 15;
  float az[8], aq[8];
#pragma unroll
  for (int m = 0; m < 8; m++) { az[m] = 0.f; aq[m] = 0.f; }
  const float* wz = &w_z[o * 128];
  const float* wq = &w_q[o * 128];
  const float* rhb = rh + b * 8192;
  for (int k = 0; k < 64; k++) {
    float wv = wz[k];
#pragma unroll
    for (int m = 0; m < 8; m++) az[m] += wv * smi_s[(l + 16 * m) * 65 + k];
  }
  for (int c = 0; c < 64; c++) {
    float wv = wq[c];
#pragma unroll
    for (int m = 0; m < 8; m++) aq[m] += wv * rhb[c * 128 + l + 16 * m];
  }
  for (int c2 = 0; c2 < 64; c2++) {
    float wvz = wz[64 + c2], wvq = wq[64 + c2];
    float g0 = wts_s[2 * c2], g1 = wts_s[2 * c2 + 1];
#pragma unroll
    for (int m = 0; m < 8; m++) {
      int nb = (m >> 2) & 1, nl = l + 16 * (m & 3);
      float gin = (nb ? g1 : g0) * smi_s[(2 * c2 + nb) * 65 + nl];
      az[m] += wvz * gin;
      aq[m] += wvq * gin;
    }
  }
  float part = 0.f;
#pragma unroll
  for (int m = 0; m < 8; m++) {
    int n = l + 16 * m;
    float z = 1.f / (1.f + expf(-az[m]));
    float q = tanhf(aq[m]);
    float h0 = smi_s[n * 65 + o];
    part += (1.f - z) * h0 + z * q;
  }
  for (int d = 8; d >= 1; d >>= 1) part += __shfl_xor(part, d, 16);
  if (l == 0) hnm[b * 64 + o] = part * (1.f / 128.f);
}

__global__ __launch_bounds__(128, 1) void k6_head(
    const float* __restrict__ state, const float* __restrict__ hnm,
    const float* __restrict__ w_m1, const float* __restrict__ b_m1,
    const float* __restrict__ w_m2, const float* __restrict__ b_m2,
    const float* __restrict__ w_m3, const float* __restrict__ b_m3,
    float* __restrict__ out) {
  int b = blockIdx.x, t = threadIdx.x;
  __shared__ float joint[70];
  __shared__ float m1s[128];
  __shared__ float red[64];
  if (t < 6) joint[t] = state[b * 1664 + t];
  if (t < 64) joint[6 + t] = hnm[b * 64 + t];
  __syncthreads();
  float a = b_m1[t];
#pragma unroll 2
  for (int k = 0; k < 70; k++) a += w_m1[t * 70 + k] * joint[k];
  m1s[t] = fmaxf(a, 0.f);
  __syncthreads();
  if (t < 64) {
    float a2 = b_m2[t];
#pragma unroll 8
    for (int k = 0; k < 128; k++) a2 += w_m2[t * 128 + k] * m1s[k];
    red[t] = fmaxf(a2, 0.f) * w_m3[t];
  }
  __syncthreads();
  for (int s = 32; s >= 1; s >>= 1) {
    if (t < s) red[t] += red[t + s];
    __syncthreads();
  }
  if (t == 0) out[b] = red[0] + b_m3[0];
}

extern "C" void kernel_launch(void* const* d_in, const int* in_sizes, int n_in,
                              void* d_out, int out_size, void* d_ws, size_t ws_size,
                              hipStream_t stream) {
  const float* state = (const float*)d_in[0];
  const float* w_in1 = (const float*)d_in[1];
  const float* b_in1 = (const float*)d_in[2];
  const float* w_in2 = (const float*)d_in[3];
  const float* b_in2 = (const float*)d_in[4];
  const float* w_c1  = (const float*)d_in[5];
  const float* b_c1  = (const float*)d_in[6];
  const float* w_c2  = (const float*)d_in[7];
  const float* b_c2  = (const float*)d_in[8];
  const float* w_ia1 = (const float*)d_in[9];
  const float* b_ia1 = (const float*)d_in[10];
  const float* w_ia2 = (const float*)d_in[11];
  const float* b_ia2 = (const float*)d_in[12];
  const float* w_s1  = (const float*)d_in[13];
  const float* b_s1  = (const float*)d_in[14];
  const float* w_s2  = (const float*)d_in[15];
  const float* b_s2  = (const float*)d_in[16];
  const float* w_a1  = (const float*)d_in[17];
  const float* b_a1  = (const float*)d_in[18];
  const float* w_a2  = (const float*)d_in[19];
  const float* b_a2  = (const float*)d_in[20];
  const float* w_a3  = (const float*)d_in[21];
  const float* b_a3  = (const float*)d_in[22];
  const float* w_z   = (const float*)d_in[23];
  const float* w_r   = (const float*)d_in[24];
  const float* w_q   = (const float*)d_in[25];
  const float* w_m1  = (const float*)d_in[26];
  const float* b_m1  = (const float*)d_in[27];
  const float* w_m2  = (const float*)d_in[28];
  const float* b_m2  = (const float*)d_in[29];
  const float* w_m3  = (const float*)d_in[30];
  const float* b_m3  = (const float*)d_in[31];
  float* ws    = (float*)d_ws;
  float* f_    = ws;
  float* R_    = ws + 262144;
  float* C_    = ws + 1835008;
  float* D_    = ws + 3407872;
  float* afa_  = ws + 6029312;
  float* smi_  = ws + 6291456;
  float* wts_  = ws + 6815744;
  float* rh_   = ws + 6823936;
  float* hnm_  = ws + 7348224;
  float* w2p_  = ws + 7352320;
  float* so_   = ws + 7376896;
  float* gst_  = ws + 7639040;
  float* se_   = ws + 7641088;
  float* out   = (float*)d_out;

  k0_pack<<<1, 256, 0, stream>>>(w_c2, w2p_);
  k1_front<<<dim3(64, 4), 128, 0, stream>>>(state, w_in1, b_in1, w_in2, b_in2, f_);
  k2_pre<<<dim3(64, 64), 128, 0, stream>>>(f_, w_c1, R_, C_, D_);
  k3_conv2<<<dim3(64, 64), 256, 0, stream>>>(f_, R_, C_, D_, b_c1, w2p_, b_c2, afa_);
  k4a_sort<<<256, 256, 0, stream>>>(state, f_, afa_, w_ia1, b_ia1, w_ia2, b_ia2,
                                    w_s1, b_s1, w_s2, b_s2, so_);
  k4b_gstate<<<64, 128, 0, stream>>>(so_, gst_);
  k4c_attn<<<256, 256, 0, stream>>>(so_, gst_, w_a1, b_a1, w_a2, b_a2, w_a3,
                                    b_a3, smi_, se_);
  k4d_wts<<<64, 128, 0, stream>>>(se_, wts_);
  k5a_r<<<dim3(4, 64), 256, 0, stream>>>(smi_, wts_, w_r, rh_);
  k5b_gru<<<dim3(4, 64), 256, 0, stream>>>(smi_, wts_, rh_, w_z, w_q, hnm_);
  k6_head<<<64, 128, 0, stream>>>(state, hnm_, w_m1, b_m1, w_m2, b_m2, w_m3,
                                  b_m3, out);
}

// Round 4
// 575.189 us; speedup vs baseline: 4.6007x; 1.4553x over previous
//
#include <hip/hip_runtime.h>
#include <math.h>

// ValueNetwork forward. conv2 via split-bf16 MFMA (3-pass hi/lo).
// ws layout (floats):
//  f    [64][32][128]        @ 0        (262144)
//  R    [64][3][64][128]     @ 262144   (1572864)
//  C    [64][3][64][128]     @ 1835008  (1572864)
//  D    [64][64][128][5]     @ 3407872  (2621440)
//  afa  [64][32][128]        @ 6029312  (262144)
//  smi  [64][128][64]        @ 6291456  (524288)
//  wts  [64][128]            @ 6815744  (8192)
//  rh   [64][64][128]        @ 6823936  (524288)
//  hnm  [64][64]             @ 7348224  (4096)
//  Apack[2][9][4][64][8] u16 @ 7352320  (18432 f32-equiv)  MFMA A-frag packed w_c2
//  so   [64][128][32]        @ 7376896  (262144)
//  gst  [64][32]             @ 7639040  (2048)
//  se   [64][128]            @ 7641088  (8192)

typedef short bf16x8 __attribute__((ext_vector_type(8)));
typedef float f32x16 __attribute__((ext_vector_type(16)));

__device__ inline unsigned int bf16_rne(float x) {
  unsigned int u = __float_as_uint(x);
  return (u + 0x7fffu + ((u >> 16) & 1u)) >> 16;
}

#define MF(A, B, Cc) __builtin_amdgcn_mfma_f32_32x32x16_bf16((A), (B), (Cc), 0, 0, 0)

// k0: pack w_c2 [o2 32][cin 64][r3][x3] fp32 -> Apack[p2][rx9][chunk4][lane64][8] bf16
// lane: o2 = lane&31, k8 = lane>>5; cin = chunk*16 + k8*8 + idx
__global__ __launch_bounds__(256) void k0_pack(const float* __restrict__ w_c2,
                                               unsigned short* __restrict__ Apack) {
  for (int idx = threadIdx.x; idx < 36864; idx += 256) {
    int p = idx / 18432, rem = idx % 18432;
    int rx = rem >> 11, r2 = rem & 2047;
    int chunk = r2 >> 9, r3 = r2 & 511;
    int lane = r3 >> 3, i8 = r3 & 7;
    int o2 = lane & 31, k8 = lane >> 5;
    int cin = chunk * 16 + k8 * 8 + i8;
    float v = w_c2[(o2 * 64 + cin) * 9 + rx];
    unsigned int hi = bf16_rne(v);
    float hif = __uint_as_float(hi << 16);
    unsigned int lo = bf16_rne(v - hif);
    Apack[idx] = (unsigned short)(p ? lo : hi);
  }
}

// front MLP: agents(7) -> 64 relu -> 32 relu, f[b][c][n]
__global__ __launch_bounds__(128) void k1_front(
    const float* __restrict__ state, const float* __restrict__ w_in1,
    const float* __restrict__ b_in1, const float* __restrict__ w_in2,
    const float* __restrict__ b_in2, float* __restrict__ f) {
  int b = blockIdx.x, nq = blockIdx.y, t = threadIdx.x;
  int row = t >> 2, lane = t & 3;
  int n = nq * 32 + row;
  __shared__ float hs[32][66];
  const float* st = state + (b * 128 + n) * 13 + 6;
  float a[7];
#pragma unroll
  for (int k = 0; k < 7; k++) a[k] = st[k];
  for (int oi = 0; oi < 16; oi++) {
    int o = lane * 16 + oi;
    float acc = b_in1[o];
#pragma unroll
    for (int k = 0; k < 7; k++) acc += w_in1[o * 7 + k] * a[k];
    hs[row][o] = fmaxf(acc, 0.f);
  }
  __syncthreads();
  for (int ci = 0; ci < 8; ci++) {
    int c = lane * 8 + ci;
    float acc = b_in2[c];
#pragma unroll 8
    for (int k = 0; k < 64; k++) acc += w_in2[c * 64 + k] * hs[row][k];
    f[(b * 32 + c) * 128 + n] = fmaxf(acc, 0.f);
  }
}

// conv1 low-rank precompute. grid (o=64, b=64), 128 threads = i.
__global__ __launch_bounds__(128) void k2_pre(
    const float* __restrict__ f, const float* __restrict__ w_c1,
    float* __restrict__ R, float* __restrict__ C, float* __restrict__ D) {
  int o = blockIdx.x, b = blockIdx.y, t = threadIdx.x;
  __shared__ float fL[32 * 128];
  __shared__ float w1s[32 * 9];
  __shared__ float wrow[32 * 9];
  __shared__ float wcol[32 * 9];
  for (int idx = t; idx < 4096; idx += 128) fL[idx] = f[b * 4096 + idx];
  for (int idx = t; idx < 288; idx += 128) w1s[idx] = w_c1[o * 288 + idx];
  __syncthreads();
  if (t < 32) {
    int c = t;
#pragma unroll
    for (int di = 0; di < 3; di++) {
      float w0 = w1s[c * 9 + di * 3 + 0], w1 = w1s[c * 9 + di * 3 + 1],
            w2 = w1s[c * 9 + di * 3 + 2];
      wrow[(c * 3 + di) * 3 + 0] = w1 + w2;
      wrow[(c * 3 + di) * 3 + 1] = w0 + w1 + w2;
      wrow[(c * 3 + di) * 3 + 2] = w0 + w1;
    }
#pragma unroll
    for (int dj = 0; dj < 3; dj++) {
      float w0 = w1s[c * 9 + 0 * 3 + dj], w1 = w1s[c * 9 + 1 * 3 + dj],
            w2 = w1s[c * 9 + 2 * 3 + dj];
      wcol[(c * 3 + dj) * 3 + 0] = w1 + w2;
      wcol[(c * 3 + dj) * 3 + 1] = w0 + w1 + w2;
      wcol[(c * 3 + dj) * 3 + 2] = w0 + w1;
    }
  }
  __syncthreads();
  int i = t;
  float r0 = 0, r1 = 0, r2 = 0, c0 = 0, c1 = 0, c2 = 0;
  float d0 = 0, d1 = 0, d2 = 0, d3 = 0, d4 = 0;
  for (int c = 0; c < 32; c++) {
    float fm = (i >= 1) ? fL[c * 128 + i - 1] : 0.f;
    float f0 = fL[c * 128 + i];
    float fp = (i < 127) ? fL[c * 128 + i + 1] : 0.f;
    const float* wr = &wrow[c * 9];
    r0 += fm * wr[0] + f0 * wr[3] + fp * wr[6];
    r1 += fm * wr[1] + f0 * wr[4] + fp * wr[7];
    r2 += fm * wr[2] + f0 * wr[5] + fp * wr[8];
    const float* wc = &wcol[c * 9];
    c0 += fm * wc[0] + f0 * wc[3] + fp * wc[6];
    c1 += fm * wc[1] + f0 * wc[4] + fp * wc[7];
    c2 += fm * wc[2] + f0 * wc[5] + fp * wc[8];
    const float* wp = &w1s[c * 9];
    d0 += fm * wp[2];
    d1 += fm * wp[1] + f0 * wp[5];
    d2 += fm * wp[0] + f0 * wp[4] + fp * wp[8];
    d3 += f0 * wp[3] + fp * wp[7];
    d4 += fp * wp[6];
  }
  R[((b * 3 + 0) * 64 + o) * 128 + i] = r0;
  R[((b * 3 + 1) * 64 + o) * 128 + i] = r1;
  R[((b * 3 + 2) * 64 + o) * 128 + i] = r2;
  C[((b * 3 + 0) * 64 + o) * 128 + i] = c0;
  C[((b * 3 + 1) * 64 + o) * 128 + i] = c1;
  C[((b * 3 + 2) * 64 + o) * 128 + i] = c2;
  float* dp = &D[((b * 64 + o) * 128 + i) * 5];
  dp[0] = d0; dp[1] = d1; dp[2] = d2; dp[3] = d3; dp[4] = d4;
}

// k3: conv2 via MFMA + softmax + afa. grid (iblk=64, b=64), 256 thr.
// Block: b, i = {2*iblk, 2*iblk+1}, all 32 o2, all 128 j. Wave = jt (32 j).
// Dynamic LDS 81920 B: G[prec 2][ipl 4][j 128][cc-stride 40] bf16 (cc 0..31 valid).
// K-loop: half (cin 32) x chunk (K=16); taps via B addressing (r->ipl, x->j+-1).
// 3-pass split: AhBh + AhBl + AlBh.
__global__ __launch_bounds__(256, 2) void k3_conv2(
    const float* __restrict__ f, const float* __restrict__ R,
    const float* __restrict__ C, const float* __restrict__ D,
    const float* __restrict__ b_c1, const unsigned short* __restrict__ Apack,
    const float* __restrict__ b_c2, float* __restrict__ afa) {
  extern __shared__ unsigned short G[];  // 40960 u16 = 81920 B
  int iblk = blockIdx.x, b = blockIdx.y, t = threadIdx.x;
  int i0 = iblk * 2;
  int lane = t & 63, jt = t >> 6;
  int nn = lane & 31;
  int ccoff_half = (lane >> 5) * 8;
  const bf16x8* A8 = (const bf16x8*)Apack;
  bf16x8 zero8 = {0, 0, 0, 0, 0, 0, 0, 0};
  f32x16 acc0 = {0, 0, 0, 0, 0, 0, 0, 0, 0, 0, 0, 0, 0, 0, 0, 0};
  f32x16 acc1 = {0, 0, 0, 0, 0, 0, 0, 0, 0, 0, 0, 0, 0, 0, 0, 0};

  // rebuild mapping: thread -> (ipl, cc-pair, j-quarter)
  int ccp = t >> 2;
  int ipl = ccp >> 4;        // 0..3
  int cpr = ccp & 15;        // cc pair within 32-half
  int q = t & 3;
  int j0r = q * 32;
  int ip = i0 - 1 + ipl;     // global conv1 row
  bool rowok = (ip >= 0 && ip <= 127);
  int ipc = ip < 0 ? 0 : (ip > 127 ? 127 : ip);
  int ic = (ipc == 0) ? 0 : ((ipc == 127) ? 2 : 1);

  for (int half = 0; half < 2; half++) {
    if (half) __syncthreads();  // MFMA of prev half done before overwrite
    // ---- rebuild G for cin = half*32 .. +31 ----
    {
      int cc = half * 32 + cpr * 2;
      float bias0 = b_c1[cc], bias1 = b_c1[cc + 1];
      float base0 = R[((b * 3 + 1) * 64 + cc) * 128 + ipc] + bias0;
      float base1 = R[((b * 3 + 1) * 64 + cc + 1) * 128 + ipc] + bias1;
      float r0v0 = 0, r0v1 = 0, r2v0 = 0, r2v1 = 0;
      if (q == 0) {
        r0v0 = R[((b * 3 + 0) * 64 + cc) * 128 + ipc] + bias0;
        r0v1 = R[((b * 3 + 0) * 64 + cc + 1) * 128 + ipc] + bias1;
      }
      if (q == 3) {
        r2v0 = R[((b * 3 + 2) * 64 + cc) * 128 + ipc] + bias0;
        r2v1 = R[((b * 3 + 2) * 64 + cc + 1) * 128 + ipc] + bias1;
      }
      const float* C0 = &C[((b * 3 + ic) * 64 + cc) * 128 + j0r];
      const float* C1 = C0 + 128;
      const float* D0 = &D[((b * 64 + cc) * 128 + ipc) * 5];
      const float* D1 = D0 + 640;
      unsigned int gbase = (unsigned)((ipl * 128 + j0r) * 40 + 2 * cpr);
#pragma unroll
      for (int s4 = 0; s4 < 8; s4++) {
        float4 c0 = ((const float4*)C0)[s4];
        float4 c1 = ((const float4*)C1)[s4];
        float v0[4], v1[4];
        v0[0] = base0 - c0.x; v0[1] = base0 - c0.y;
        v0[2] = base0 - c0.z; v0[3] = base0 - c0.w;
        v1[0] = base1 - c1.x; v1[1] = base1 - c1.y;
        v1[2] = base1 - c1.z; v1[3] = base1 - c1.w;
        if (q == 0 && s4 == 0) { v0[0] = r0v0 - c0.x; v1[0] = r0v1 - c1.x; }
        if (q == 3 && s4 == 7) { v0[3] = r2v0 - c0.w; v1[3] = r2v1 - c1.w; }
#pragma unroll
        for (int t5 = 0; t5 < 5; t5++) {
          int rel = (ip - 2 + t5) - (j0r + s4 * 4);
          if (rel >= 0 && rel < 4) { v0[rel] += D0[t5]; v1[rel] += D1[t5]; }
        }
#pragma unroll
        for (int k = 0; k < 4; k++) {
          float a0 = rowok ? fmaxf(v0[k], 0.f) : 0.f;
          float a1 = rowok ? fmaxf(v1[k], 0.f) : 0.f;
          unsigned int h0 = bf16_rne(a0), h1 = bf16_rne(a1);
          float l0f = a0 - __uint_as_float(h0 << 16);
          float l1f = a1 - __uint_as_float(h1 << 16);
          unsigned int l0 = bf16_rne(l0f), l1 = bf16_rne(l1f);
          unsigned int off = gbase + (unsigned)((s4 * 4 + k) * 40);
          *(unsigned int*)&G[off] = h0 | (h1 << 16);
          *(unsigned int*)&G[off + 20480] = l0 | (l1 << 16);
        }
      }
    }
    __syncthreads();
    // ---- MFMA chunks ----
    for (int cb = 0; cb < 2; cb++) {
      int chunk = half * 2 + cb;
      bf16x8 Ah[9], Al[9];
#pragma unroll
      for (int rx = 0; rx < 9; rx++) {
        Ah[rx] = A8[(rx * 4 + chunk) * 64 + lane];
        Al[rx] = A8[((9 + rx) * 4 + chunk) * 64 + lane];
      }
      int ccoff = cb * 16 + ccoff_half;
#pragma unroll
      for (int rowidx = 0; rowidx < 4; rowidx++) {
#pragma unroll
        for (int x = 0; x < 3; x++) {
          int imgj = jt * 32 + nn + x - 1;
          int ij = imgj < 0 ? 0 : (imgj > 127 ? 127 : imgj);
          int off = (rowidx * 128 + ij) * 40 + ccoff;
          bf16x8 bh = *(const bf16x8*)&G[off];
          bf16x8 bl = *(const bf16x8*)&G[off + 20480];
          if (imgj < 0 || imgj > 127) { bh = zero8; bl = zero8; }
          if (rowidx == 0) {
            acc0 = MF(Ah[x], bh, acc0);
            acc0 = MF(Ah[x], bl, acc0);
            acc0 = MF(Al[x], bh, acc0);
          } else if (rowidx == 1) {
            acc0 = MF(Ah[3 + x], bh, acc0);
            acc0 = MF(Ah[3 + x], bl, acc0);
            acc0 = MF(Al[3 + x], bh, acc0);
            acc1 = MF(Ah[x], bh, acc1);
            acc1 = MF(Ah[x], bl, acc1);
            acc1 = MF(Al[x], bh, acc1);
          } else if (rowidx == 2) {
            acc0 = MF(Ah[6 + x], bh, acc0);
            acc0 = MF(Ah[6 + x], bl, acc0);
            acc0 = MF(Al[6 + x], bh, acc0);
            acc1 = MF(Ah[3 + x], bh, acc1);
            acc1 = MF(Ah[3 + x], bl, acc1);
            acc1 = MF(Al[3 + x], bh, acc1);
          } else {
            acc1 = MF(Ah[6 + x], bh, acc1);
            acc1 = MF(Ah[6 + x], bl, acc1);
            acc1 = MF(Al[6 + x], bh, acc1);
          }
        }
      }
    }
  }
  __syncthreads();
  // ---- epilogue: logits -> LDS, f -> LDS ----
  float* logits = (float*)G;          // 8192 f32 (32 KB)
  float* fbuf = (float*)G + 8192;     // 4096 f32 (16 KB)
#pragma unroll
  for (int reg = 0; reg < 16; reg++) {
    int o2 = (reg & 3) + 8 * (reg >> 2) + 4 * (lane >> 5);
    int j = jt * 32 + nn;
    logits[(0 * 32 + o2) * 128 + j] = acc0[reg];
    logits[(1 * 32 + o2) * 128 + j] = acc1[reg];
  }
  for (int idx = t; idx < 1024; idx += 256)
    ((float4*)fbuf)[idx] = ((const float4*)(f + b * 4096))[idx];
  __syncthreads();
  // ---- softmax over j + weighted pair reduction ----
  {
    int i2 = t >> 7, o2e = (t >> 2) & 31, qd = t & 3;
    const float* lrow = &logits[(i2 * 32 + o2e) * 128 + qd * 32];
    float bias2 = b_c2[o2e];
    float vals[32];
    float mx = -3.0e38f;
#pragma unroll 8
    for (int s = 0; s < 32; s++) {
      vals[s] = lrow[s] + bias2;
      mx = fmaxf(mx, vals[s]);
    }
    mx = fmaxf(mx, __shfl_xor(mx, 1));
    mx = fmaxf(mx, __shfl_xor(mx, 2));
    float sum = 0.f;
#pragma unroll 8
    for (int s = 0; s < 32; s++) {
      vals[s] = expf(vals[s] - mx);
      sum += vals[s];
    }
    sum += __shfl_xor(sum, 1);
    sum += __shfl_xor(sum, 2);
    float inv = 1.f / sum;
    int gi = i0 + i2;
    float fi = fbuf[o2e * 128 + gi];
    float part = 0.f;
#pragma unroll 8
    for (int s = 0; s < 32; s++) {
      int j = qd * 32 + s;
      float w = vals[s] * inv;
      part += w * (fi - fbuf[o2e * 128 + j]);
      if (j == gi) part += w * fi;
    }
    part += __shfl_xor(part, 1);
    part += __shfl_xor(part, 2);
    if (qd == 0) afa[(b * 32 + o2e) * 128 + gi] = part;
  }
}

// k4a: per (b,n): x -> h1 -> ia||self -> s1 -> so. grid 256 blocks, 256 thr.
__global__ __launch_bounds__(256) void k4a_sort(
    const float* __restrict__ state, const float* __restrict__ f,
    const float* __restrict__ afa, const float* __restrict__ w_ia1,
    const float* __restrict__ b_ia1, const float* __restrict__ w_ia2,
    const float* __restrict__ b_ia2, const float* __restrict__ w_s1,
    const float* __restrict__ b_s1, const float* __restrict__ w_s2,
    const float* __restrict__ b_s2, float* __restrict__ so_g) {
  int blk = blockIdx.x;
  int b = blk >> 2, nq = blk & 3;
  int t = threadIdx.x, row = t >> 3, lane = t & 7;
  int n = nq * 32 + row;
  __shared__ float bufA[32][40];
  __shared__ float bufB[32][72];
  {
    int c0 = lane * 4;
    float4 av = *(const float4*)&afa[b * 4096 + n * 32 + c0];
    bufA[row][c0 + 0] = f[b * 4096 + (c0 + 0) * 128 + n] + av.x;
    bufA[row][c0 + 1] = f[b * 4096 + (c0 + 1) * 128 + n] + av.y;
    bufA[row][c0 + 2] = f[b * 4096 + (c0 + 2) * 128 + n] + av.z;
    bufA[row][c0 + 3] = f[b * 4096 + (c0 + 3) * 128 + n] + av.w;
  }
  __syncthreads();
#pragma unroll
  for (int oi = 0; oi < 8; oi++) {
    int o = lane * 8 + oi;
    float a = b_ia1[o];
#pragma unroll 8
    for (int c = 0; c < 32; c++) a += w_ia1[o * 32 + c] * bufA[row][c];
    bufB[row][o] = fmaxf(a, 0.f);
  }
  __syncthreads();
  {
    float r0[4];
#pragma unroll
    for (int oi = 0; oi < 4; oi++) {
      int o = lane * 4 + oi;
      float a = b_ia2[o];
#pragma unroll 8
      for (int k = 0; k < 64; k++) a += w_ia2[o * 64 + k] * bufB[row][k];
      r0[oi] = a;
    }
    __syncthreads();
#pragma unroll
    for (int oi = 0; oi < 4; oi++) bufA[row][lane * 4 + oi] = r0[oi];
    if (lane == 0) {
#pragma unroll
      for (int k = 0; k < 6; k++)
        bufA[row][32 + k] = state[(b * 128 + n) * 13 + k];
    }
  }
  __syncthreads();
#pragma unroll
  for (int oi = 0; oi < 8; oi++) {
    int o = lane * 8 + oi;
    float a = b_s1[o];
#pragma unroll 2
    for (int k = 0; k < 38; k++) a += w_s1[o * 38 + k] * bufA[row][k];
    bufB[row][o] = fmaxf(a, 0.f);
  }
  __syncthreads();
#pragma unroll
  for (int oi = 0; oi < 4; oi++) {
    int o = lane * 4 + oi;
    float a = b_s2[o];
#pragma unroll 8
    for (int k = 0; k < 64; k++) a += w_s2[o * 64 + k] * bufB[row][k];
    so_g[(b * 128 + n) * 32 + o] = a;
  }
}

__global__ __launch_bounds__(128) void k4b_gstate(const float* __restrict__ so_g,
                                                  float* __restrict__ gst) {
  int b = blockIdx.x, t = threadIdx.x;
  int c = t & 31, part = t >> 5;
  __shared__ float red[4][32];
  float a = 0.f;
  for (int nn = 0; nn < 32; nn++) a += so_g[(b * 128 + part * 32 + nn) * 32 + c];
  red[part][c] = a;
  __syncthreads();
  if (t < 32) gst[b * 32 + t] =
      (red[0][t] + red[1][t] + red[2][t] + red[3][t]) * (1.f / 128.f);
}

__global__ __launch_bounds__(256) void k4c_attn(
    const float* __restrict__ so_g, const float* __restrict__ gst,
    const float* __restrict__ w_a1, const float* __restrict__ b_a1,
    const float* __restrict__ w_a2, const float* __restrict__ b_a2,
    const float* __restrict__ w_a3, const float* __restrict__ b_a3,
    float* __restrict__ smi, float* __restrict__ se_g) {
  int blk = blockIdx.x;
  int b = blk >> 2, nq = blk & 3;
  int t = threadIdx.x, row = t >> 3, lane = t & 7;
  int n = nq * 32 + row;
  __shared__ float bufA[32][72];
  __shared__ float bufB[32][72];
  {
    int c0 = lane * 4;
    float4 sv = *(const float4*)&so_g[(b * 128 + n) * 32 + c0];
    float4 gv = *(const float4*)&gst[b * 32 + c0];
    *(float4*)&bufA[row][c0] = sv;
    *(float4*)&bufA[row][32 + c0] = gv;
    *(float4*)&smi[b * 8192 + n * 64 + c0] = sv;
    *(float4*)&smi[b * 8192 + n * 64 + 32 + c0] = gv;
  }
  __syncthreads();
#pragma unroll
  for (int oi = 0; oi < 8; oi++) {
    int o = lane * 8 + oi;
    float a = b_a1[o];
#pragma unroll 8
    for (int k = 0; k < 64; k++) a += w_a1[o * 64 + k] * bufA[row][k];
    bufB[row][o] = fmaxf(a, 0.f);
  }
  __syncthreads();
  float ps = 0.f;
#pragma unroll
  for (int oi = 0; oi < 4; oi++) {
    int o = lane * 4 + oi;
    float a = b_a2[o];
#pragma unroll 8
    for (int k = 0; k < 64; k++) a += w_a2[o * 64 + k] * bufB[row][k];
    ps += w_a3[o] * fmaxf(a, 0.f);
  }
  for (int d = 4; d >= 1; d >>= 1) ps += __shfl_xor(ps, d, 8);
  if (lane == 0) {
    float sc = ps + b_a3[0];
    se_g[b * 128 + n] = (sc != 0.f) ? expf(sc) : 0.f;
  }
}

__global__ __launch_bounds__(128) void k4d_wts(const float* __restrict__ se_g,
                                               float* __restrict__ wts) {
  int b = blockIdx.x, n = threadIdx.x;
  __shared__ float red[128];
  float se = se_g[b * 128 + n];
  red[n] = se;
  __syncthreads();
  for (int s = 64; s >= 1; s >>= 1) {
    if (n < s) red[n] += red[n + s];
    __syncthreads();
  }
  wts[b * 128 + n] = se / red[0];
}

// GRU r-gate
__global__ __launch_bounds__(256) void k5a_r(
    const float* __restrict__ smi, const float* __restrict__ wts,
    const float* __restrict__ w_r, float* __restrict__ rh) {
  int cch = blockIdx.x, b = blockIdx.y, t = threadIdx.x;
  __shared__ float smi_s[128 * 65];
  __shared__ float wts_s[128];
  for (int idx = t; idx < 8192; idx += 256) {
    int n = idx >> 6, k = idx & 63;
    smi_s[n * 65 + k] = smi[b * 8192 + idx];
  }
  if (t < 128) wts_s[t] = wts[b * 128 + t];
  __syncthreads();
  int c = cch * 16 + (t >> 4), l = t & 15;
  float accs[8];
#pragma unroll
  for (int m = 0; m < 8; m++) accs[m] = 0.f;
  const float* wr = &w_r[c * 128];
  for (int k = 0; k < 64; k++) {
    float wv = wr[k];
#pragma unroll
    for (int m = 0; m < 8; m++) accs[m] += wv * smi_s[(l + 16 * m) * 65 + k];
  }
  for (int c2 = 0; c2 < 64; c2++) {
    float wv = wr[64 + c2];
    float g0 = wts_s[2 * c2], g1 = wts_s[2 * c2 + 1];
#pragma unroll
    for (int m = 0; m < 8; m++) {
      int nb = (m >> 2) & 1, nl = l + 16 * (m & 3);
      accs[m] += wv * ((nb ? g1 : g0) * smi_s[(2 * c2 + nb) * 65 + nl]);
    }
  }
#pragma unroll
  for (int m = 0; m < 8; m++) {
    int n = l + 16 * m;
    float r = 1.f / (1.f + expf(-accs[m]));
    rh[(b * 64 + c) * 128 + n] = r * smi_s[n * 65 + c];
  }
}

// GRU z, q, hn, mean over n
__global__ __launch_bounds__(256) void k5b_gru(
    const float* __restrict__ smi, const float* __restrict__ wts,
    const float* __restrict__ rh, const float* __restrict__ w_z,
    const float* __restrict__ w_q, float* __restrict__ hnm) {
  int och = blockIdx.x, b = blockIdx.y, t = threadIdx.x;
  __shared__ float smi_s[128 * 65];
  __shared__ float wts_s[128];
  for (int idx = t; idx < 8192; idx += 256) {
    int n = idx >> 6, k = idx & 63;
    smi_s[n * 65 + k] = smi[b * 8192 + idx];
  }
  if (t < 128) wts_s[t] = wts[b * 128 + t];
  __syncthreads();
  int o = och * 16 + (t >> 4), l = t & 15;
  float az[8], aq[8];
#pragma unroll
  for (int m = 0; m < 8; m++) { az[m] = 0.f; aq[m] = 0.f; }
  const float* wz = &w_z[o * 128];
  const float* wq = &w_q[o * 128];
  const float* rhb = rh + b * 8192;
  for (int k = 0; k < 64; k++) {
    float wv = wz[k];
#pragma unroll
    for (int m = 0; m < 8; m++) az[m] += wv * smi_s[(l + 16 * m) * 65 + k];
  }
  for (int c = 0; c < 64; c++) {
    float wv = wq[c];
#pragma unroll
    for (int m = 0; m < 8; m++) aq[m] += wv * rhb[c * 128 + l + 16 * m];
  }
  for (int c2 = 0; c2 < 64; c2++) {
    float wvz = wz[64 + c2], wvq = wq[64 + c2];
    float g0 = wts_s[2 * c2], g1 = wts_s[2 * c2 + 1];
#pragma unroll
    for (int m = 0; m < 8; m++) {
      int nb = (m >> 2) & 1, nl = l + 16 * (m & 3);
      float gin = (nb ? g1 : g0) * smi_s[(2 * c2 + nb) * 65 + nl];
      az[m] += wvz * gin;
      aq[m] += wvq * gin;
    }
  }
  float part = 0.f;
#pragma unroll
  for (int m = 0; m < 8; m++) {
    int n = l + 16 * m;
    float z = 1.f / (1.f + expf(-az[m]));
    float q = tanhf(aq[m]);
    float h0 = smi_s[n * 65 + o];
    part += (1.f - z) * h0 + z * q;
  }
  for (int d = 8; d >= 1; d >>= 1) part += __shfl_xor(part, d, 16);
  if (l == 0) hnm[b * 64 + o] = part * (1.f / 128.f);
}

__global__ __launch_bounds__(128, 1) void k6_head(
    const float* __restrict__ state, const float* __restrict__ hnm,
    const float* __restrict__ w_m1, const float* __restrict__ b_m1,
    const float* __restrict__ w_m2, const float* __restrict__ b_m2,
    const float* __restrict__ w_m3, const float* __restrict__ b_m3,
    float* __restrict__ out) {
  int b = blockIdx.x, t = threadIdx.x;
  __shared__ float joint[70];
  __shared__ float m1s[128];
  __shared__ float red[64];
  if (t < 6) joint[t] = state[b * 1664 + t];
  if (t < 64) joint[6 + t] = hnm[b * 64 + t];
  __syncthreads();
  float a = b_m1[t];
#pragma unroll 2
  for (int k = 0; k < 70; k++) a += w_m1[t * 70 + k] * joint[k];
  m1s[t] = fmaxf(a, 0.f);
  __syncthreads();
  if (t < 64) {
    float a2 = b_m2[t];
#pragma unroll 8
    for (int k = 0; k < 128; k++) a2 += w_m2[t * 128 + k] * m1s[k];
    red[t] = fmaxf(a2, 0.f) * w_m3[t];
  }
  __syncthreads();
  for (int s = 32; s >= 1; s >>= 1) {
    if (t < s) red[t] += red[t + s];
    __syncthreads();
  }
  if (t == 0) out[b] = red[0] + b_m3[0];
}

extern "C" void kernel_launch(void* const* d_in, const int* in_sizes, int n_in,
                              void* d_out, int out_size, void* d_ws, size_t ws_size,
                              hipStream_t stream) {
  const float* state = (const float*)d_in[0];
  const float* w_in1 = (const float*)d_in[1];
  const float* b_in1 = (const float*)d_in[2];
  const float* w_in2 = (const float*)d_in[3];
  const float* b_in2 = (const float*)d_in[4];
  const float* w_c1  = (const float*)d_in[5];
  const float* b_c1  = (const float*)d_in[6];
  const float* w_c2  = (const float*)d_in[7];
  const float* b_c2  = (const float*)d_in[8];
  const float* w_ia1 = (const float*)d_in[9];
  const float* b_ia1 = (const float*)d_in[10];
  const float* w_ia2 = (const float*)d_in[11];
  const float* b_ia2 = (const float*)d_in[12];
  const float* w_s1  = (const float*)d_in[13];
  const float* b_s1  = (const float*)d_in[14];
  const float* w_s2  = (const float*)d_in[15];
  const float* b_s2  = (const float*)d_in[16];
  const float* w_a1  = (const float*)d_in[17];
  const float* b_a1  = (const float*)d_in[18];
  const float* w_a2  = (const float*)d_in[19];
  const float* b_a2  = (const float*)d_in[20];
  const float* w_a3  = (const float*)d_in[21];
  const float* b_a3  = (const float*)d_in[22];
  const float* w_z   = (const float*)d_in[23];
  const float* w_r   = (const float*)d_in[24];
  const float* w_q   = (const float*)d_in[25];
  const float* w_m1  = (const float*)d_in[26];
  const float* b_m1  = (const float*)d_in[27];
  const float* w_m2  = (const float*)d_in[28];
  const float* b_m2  = (const float*)d_in[29];
  const float* w_m3  = (const float*)d_in[30];
  const float* b_m3  = (const float*)d_in[31];
  float* ws    = (float*)d_ws;
  float* f_    = ws;
  float* R_    = ws + 262144;
  float* C_    = ws + 1835008;
  float* D_    = ws + 3407872;
  float* afa_  = ws + 6029312;
  float* smi_  = ws + 6291456;
  float* wts_  = ws + 6815744;
  float* rh_   = ws + 6823936;
  float* hnm_  = ws + 7348224;
  unsigned short* Apack_ = (unsigned short*)(ws + 7352320);
  float* so_   = ws + 7376896;
  float* gst_  = ws + 7639040;
  float* se_   = ws + 7641088;
  float* out   = (float*)d_out;

  k0_pack<<<1, 256, 0, stream>>>(w_c2, Apack_);
  k1_front<<<dim3(64, 4), 128, 0, stream>>>(state, w_in1, b_in1, w_in2, b_in2, f_);
  k2_pre<<<dim3(64, 64), 128, 0, stream>>>(f_, w_c1, R_, C_, D_);
  k3_conv2<<<dim3(64, 64), 256, 81920, stream>>>(f_, R_, C_, D_, b_c1, Apack_,
                                                 b_c2, afa_);
  k4a_sort<<<256, 256, 0, stream>>>(state, f_, afa_, w_ia1, b_ia1, w_ia2, b_ia2,
                                    w_s1, b_s1, w_s2, b_s2, so_);
  k4b_gstate<<<64, 128, 0, stream>>>(so_, gst_);
  k4c_attn<<<256, 256, 0, stream>>>(so_, gst_, w_a1, b_a1, w_a2, b_a2, w_a3,
                                    b_a3, smi_, se_);
  k4d_wts<<<64, 128, 0, stream>>>(se_, wts_);
  k5a_r<<<dim3(4, 64), 256, 0, stream>>>(smi_, wts_, w_r, rh_);
  k5b_gru<<<dim3(4, 64), 256, 0, stream>>>(smi_, wts_, rh_, w_z, w_q, hnm_);
  k6_head<<<64, 128, 0, stream>>>(state, hnm_, w_m1, b_m1, w_m2, b_m2, w_m3,
                                  b_m3, out);
}